// Round 1
// baseline (818.045 us; speedup 1.0000x reference)
//
#include <hip/hip_runtime.h>
#include <hip/hip_bf16.h>

#define BQ   4
#define SQL  2048
#define DM   256
#define NH   8
#define DEP  32
#define DFF_ 1024
#define NROWS (BQ*SQL)      // 8192
#define LNEPS 1e-6f

// ---- workspace layout (float offsets) ----
#define OFF_Q   0u                   // 8192*256
#define OFF_K   2097152u
#define OFF_V   4194304u
#define OFF_K2  6291456u             // 65536 (bh,s)
#define OFF_PN  6356992u             // 4*65536*32 partial numerators
#define OFF_PD  14745600u            // 4*65536  partial denominators
#define OFF_CTX 15007744u            // 8192*256
#define OFF_O1  17104896u            // 8192*256
#define OFF_MID 0u                   // 8192*1024, aliases q/k/v/pn (dead by then)

// ---------------- QKV projection: q/k/v = x @ W + b ----------------
__global__ __launch_bounds__(256) void k_qkv(
    const float* __restrict__ x,
    const float* __restrict__ wq, const float* __restrict__ bq,
    const float* __restrict__ wk, const float* __restrict__ bk,
    const float* __restrict__ wv, const float* __restrict__ bv,
    float* __restrict__ q, float* __restrict__ k, float* __restrict__ v)
{
    __shared__ float xs[16][256];
    const int t = threadIdx.x;
    const int row0 = blockIdx.x * 16;
    {
        const float4* src = (const float4*)(x + row0 * DM);
        float4* dst = (float4*)xs;
#pragma unroll
        for (int i = 0; i < 4; ++i) dst[i * 256 + t] = src[i * 256 + t];
    }
    __syncthreads();
    float aq[16], ak[16], av[16];
#pragma unroll
    for (int i = 0; i < 16; ++i) { aq[i] = 0.f; ak[i] = 0.f; av[i] = 0.f; }
    for (int kk = 0; kk < 256; kk += 4) {
        float q0 = wq[(kk + 0) * DM + t], q1 = wq[(kk + 1) * DM + t];
        float q2 = wq[(kk + 2) * DM + t], q3 = wq[(kk + 3) * DM + t];
        float k0 = wk[(kk + 0) * DM + t], k1 = wk[(kk + 1) * DM + t];
        float k2v = wk[(kk + 2) * DM + t], k3 = wk[(kk + 3) * DM + t];
        float v0 = wv[(kk + 0) * DM + t], v1 = wv[(kk + 1) * DM + t];
        float v2 = wv[(kk + 2) * DM + t], v3 = wv[(kk + 3) * DM + t];
#pragma unroll
        for (int i = 0; i < 16; ++i) {
            float4 xv = *(const float4*)&xs[i][kk];
            aq[i] = fmaf(xv.x, q0, fmaf(xv.y, q1, fmaf(xv.z, q2, fmaf(xv.w, q3, aq[i]))));
            ak[i] = fmaf(xv.x, k0, fmaf(xv.y, k1, fmaf(xv.z, k2v, fmaf(xv.w, k3, ak[i]))));
            av[i] = fmaf(xv.x, v0, fmaf(xv.y, v1, fmaf(xv.z, v2, fmaf(xv.w, v3, av[i]))));
        }
    }
    const float bqv = bq[t], bkv = bk[t], bvv = bv[t];
#pragma unroll
    for (int i = 0; i < 16; ++i) {
        q[(row0 + i) * DM + t] = aq[i] + bqv;
        k[(row0 + i) * DM + t] = ak[i] + bkv;
        v[(row0 + i) * DM + t] = av[i] + bvv;
    }
}

// ---------------- k2[bh*S + s] = sum_d k^2 ----------------
__global__ __launch_bounds__(256) void k_k2(const float* __restrict__ k,
                                            float* __restrict__ k2)
{
    const int gid = blockIdx.x * 256 + threadIdx.x;   // 0..65535
    const int bh = gid >> 11, s = gid & 2047;
    const int b = bh >> 3, h = bh & 7;
    const float4* src = (const float4*)k;
    float acc = 0.f;
#pragma unroll
    for (int ii = 0; ii < 8; ++ii) {
        float4 a = src[(b * SQL + s) * 64 + h * 8 + ii];
        acc += a.x * a.x + a.y * a.y + a.z * a.z + a.w * a.w;
    }
    k2[gid] = acc;
}

// ---------------- attention, flash-style, KSPLIT=4 ----------------
// softmax arg = exp(-0.5*d) in (0,1] -> no max tracking needed; partials additive.
__global__ __launch_bounds__(256) void k_attn(
    const float* __restrict__ q, const float* __restrict__ k,
    const float* __restrict__ v, const float* __restrict__ k2,
    float* __restrict__ pnum, float* __restrict__ pden)
{
    __shared__ float ks_[64][32];
    __shared__ float vs_[64][32];
    __shared__ float k2s[64];
    const int t = threadIdx.x;
    const int bid = blockIdx.x;
    const int ksplit = bid & 3;
    const int qt = (bid >> 2) & 7;
    const int bh = bid >> 5;
    const int b = bh >> 3, h = bh & 7;
    const int sq = qt * 256 + t;
    const int gq = b * SQL + sq;

    float4 qv[8];
    {
        const float4* qsrc = (const float4*)q;
#pragma unroll
        for (int ii = 0; ii < 8; ++ii) qv[ii] = qsrc[gq * 64 + h * 8 + ii];
    }
    float q2v = 0.f;
#pragma unroll
    for (int ii = 0; ii < 8; ++ii)
        q2v += qv[ii].x * qv[ii].x + qv[ii].y * qv[ii].y + qv[ii].z * qv[ii].z + qv[ii].w * qv[ii].w;

    float4 num[8];
#pragma unroll
    for (int ii = 0; ii < 8; ++ii) num[ii] = make_float4(0.f, 0.f, 0.f, 0.f);
    float den = 0.f;

    const int key_base = ksplit * 512;
    for (int tile = 0; tile < 8; ++tile) {
        const int key0 = key_base + tile * 64;
        {
            const float4* ksrc = (const float4*)k;
            const float4* vsrc = (const float4*)v;
#pragma unroll
            for (int it = 0; it < 2; ++it) {
                int f4 = it * 256 + t;
                int key = f4 >> 3, dd4 = f4 & 7;
                int srcidx = (b * SQL + key0 + key) * 64 + h * 8 + dd4;
                ((float4*)ks_)[f4] = ksrc[srcidx];
                ((float4*)vs_)[f4] = vsrc[srcidx];
            }
            if (t < 64) k2s[t] = k2[bh * SQL + key0 + t];
        }
        __syncthreads();
#pragma unroll 4
        for (int j = 0; j < 64; ++j) {
            const float4* kj = (const float4*)ks_[j];
            float dot = 0.f;
#pragma unroll
            for (int ii = 0; ii < 8; ++ii) {
                float4 kk4 = kj[ii];
                dot += qv[ii].x * kk4.x + qv[ii].y * kk4.y + qv[ii].z * kk4.z + qv[ii].w * kk4.w;
            }
            float d = q2v - 2.f * dot + k2s[j];
            float w = __expf(__expf(-0.5f * d));
            den += w;
            const float4* vj = (const float4*)vs_[j];
#pragma unroll
            for (int ii = 0; ii < 8; ++ii) {
                float4 vv = vj[ii];
                num[ii].x = fmaf(w, vv.x, num[ii].x);
                num[ii].y = fmaf(w, vv.y, num[ii].y);
                num[ii].z = fmaf(w, vv.z, num[ii].z);
                num[ii].w = fmaf(w, vv.w, num[ii].w);
            }
        }
        __syncthreads();
    }
    const int idx = bh * SQL + sq;     // 0..65535
    float4* pdst = (float4*)pnum;
#pragma unroll
    for (int ii = 0; ii < 8; ++ii) pdst[(ksplit * 65536 + idx) * 8 + ii] = num[ii];
    pden[ksplit * 65536 + idx] = den;
}

// ---------------- combine partials -> ctx[b,s,h*32+d] ----------------
__global__ __launch_bounds__(256) void k_combine(
    const float* __restrict__ pnum, const float* __restrict__ pden,
    float* __restrict__ ctx)
{
    const int gid = blockIdx.x * 256 + threadIdx.x;   // 0..524287
    const int bhs = gid >> 3, ii = gid & 7;
    const float4* pn = (const float4*)pnum;
    float4 s = make_float4(0.f, 0.f, 0.f, 0.f);
    float dsum = 0.f;
#pragma unroll
    for (int ksp = 0; ksp < 4; ++ksp) {
        float4 a = pn[(ksp * 65536 + bhs) * 8 + ii];
        s.x += a.x; s.y += a.y; s.z += a.z; s.w += a.w;
        dsum += pden[ksp * 65536 + bhs];
    }
    const float inv = 1.f / dsum;
    const int bh = bhs >> 11, sl = bhs & 2047;
    const int b = bh >> 3, h = bh & 7;
    ((float4*)ctx)[(b * SQL + sl) * 64 + h * 8 + ii] =
        make_float4(s.x * inv, s.y * inv, s.z * inv, s.w * inv);
}

// ---------------- out1 = LN(x + ctx@wo + wob) ----------------
__global__ __launch_bounds__(256) void k_wo_ln1(
    const float* __restrict__ ctx, const float* __restrict__ wo,
    const float* __restrict__ wob, const float* __restrict__ x,
    const float* __restrict__ g1, const float* __restrict__ b1,
    float* __restrict__ out1)
{
    __shared__ float cs[16][256];
    __shared__ float mus[16], rss[16];
    const int t = threadIdx.x;
    const int row0 = blockIdx.x * 16;
    {
        const float4* src = (const float4*)(ctx + row0 * DM);
        float4* dst = (float4*)cs;
#pragma unroll
        for (int i = 0; i < 4; ++i) dst[i * 256 + t] = src[i * 256 + t];
    }
    __syncthreads();
    float acc[16];
#pragma unroll
    for (int i = 0; i < 16; ++i) acc[i] = 0.f;
    for (int kk = 0; kk < 256; kk += 4) {
        float w0 = wo[(kk + 0) * DM + t], w1 = wo[(kk + 1) * DM + t];
        float w2 = wo[(kk + 2) * DM + t], w3 = wo[(kk + 3) * DM + t];
#pragma unroll
        for (int i = 0; i < 16; ++i) {
            float4 xv = *(const float4*)&cs[i][kk];
            acc[i] = fmaf(xv.x, w0, fmaf(xv.y, w1, fmaf(xv.z, w2, fmaf(xv.w, w3, acc[i]))));
        }
    }
    __syncthreads();
    const float wobv = wob[t];
#pragma unroll
    for (int i = 0; i < 16; ++i) {
        float y = acc[i] + wobv + x[(row0 + i) * DM + t];
        cs[i][t] = y;
    }
    __syncthreads();
    const int w = t >> 6, l = t & 63;
#pragma unroll
    for (int ri = 0; ri < 4; ++ri) {
        int i = w * 4 + ri;
        float s = 0.f, ss = 0.f;
#pragma unroll
        for (int c = 0; c < 4; ++c) { float vv = cs[i][l + c * 64]; s += vv; ss += vv * vv; }
#pragma unroll
        for (int off = 32; off; off >>= 1) { s += __shfl_xor(s, off); ss += __shfl_xor(ss, off); }
        if (l == 0) {
            float mu = s * (1.f / 256.f);
            float var = ss * (1.f / 256.f) - mu * mu;
            mus[i] = mu; rss[i] = rsqrtf(var + LNEPS);
        }
    }
    __syncthreads();
    const float gv = g1[t], bv = b1[t];
#pragma unroll
    for (int i = 0; i < 16; ++i)
        out1[(row0 + i) * DM + t] = (cs[i][t] - mus[i]) * rss[i] * gv + bv;
}

// ---------------- mid = relu(out1 @ W1 + b1) ----------------
__global__ __launch_bounds__(256) void k_ffn1(
    const float* __restrict__ out1, const float* __restrict__ w1,
    const float* __restrict__ b1f, float* __restrict__ mid)
{
    __shared__ float cs[16][256];
    const int t = threadIdx.x;
    const int rt = blockIdx.x >> 2;
    const int cg = blockIdx.x & 3;
    const int row0 = rt * 16;
    const int col = cg * 256 + t;
    {
        const float4* src = (const float4*)(out1 + row0 * DM);
        float4* dst = (float4*)cs;
#pragma unroll
        for (int i = 0; i < 4; ++i) dst[i * 256 + t] = src[i * 256 + t];
    }
    __syncthreads();
    float acc[16];
#pragma unroll
    for (int i = 0; i < 16; ++i) acc[i] = 0.f;
    for (int kk = 0; kk < 256; kk += 4) {
        float w0 = w1[(kk + 0) * DFF_ + col], w1v = w1[(kk + 1) * DFF_ + col];
        float w2 = w1[(kk + 2) * DFF_ + col], w3 = w1[(kk + 3) * DFF_ + col];
#pragma unroll
        for (int i = 0; i < 16; ++i) {
            float4 xv = *(const float4*)&cs[i][kk];
            acc[i] = fmaf(xv.x, w0, fmaf(xv.y, w1v, fmaf(xv.z, w2, fmaf(xv.w, w3, acc[i]))));
        }
    }
    const float bv = b1f[col];
#pragma unroll
    for (int i = 0; i < 16; ++i)
        mid[(row0 + i) * DFF_ + col] = fmaxf(acc[i] + bv, 0.f);
}

// ---------------- out = LN(out1 + mid @ W2 + b2) ----------------
__global__ __launch_bounds__(256) void k_ffn2_ln2(
    const float* __restrict__ mid, const float* __restrict__ w2,
    const float* __restrict__ b2f, const float* __restrict__ out1,
    const float* __restrict__ g2, const float* __restrict__ b2ln,
    float* __restrict__ out)
{
    __shared__ float ms[8][1024];
    __shared__ float ys[8][256];
    __shared__ float mus[8], rss[8];
    const int t = threadIdx.x;
    const int row0 = blockIdx.x * 8;
    {
        const float4* src = (const float4*)(mid + row0 * DFF_);
        float4* dst = (float4*)ms;
#pragma unroll
        for (int i = 0; i < 8; ++i) dst[i * 256 + t] = src[i * 256 + t];
    }
    __syncthreads();
    float acc[8];
#pragma unroll
    for (int i = 0; i < 8; ++i) acc[i] = 0.f;
    for (int kk = 0; kk < 1024; kk += 4) {
        float w0 = w2[(kk + 0) * DM + t], w1v = w2[(kk + 1) * DM + t];
        float w2v = w2[(kk + 2) * DM + t], w3 = w2[(kk + 3) * DM + t];
#pragma unroll
        for (int i = 0; i < 8; ++i) {
            float4 xv = *(const float4*)&ms[i][kk];
            acc[i] = fmaf(xv.x, w0, fmaf(xv.y, w1v, fmaf(xv.z, w2v, fmaf(xv.w, w3, acc[i]))));
        }
    }
    const float bv = b2f[t];
#pragma unroll
    for (int i = 0; i < 8; ++i) {
        float y = acc[i] + bv + out1[(row0 + i) * DM + t];
        ys[i][t] = y;
    }
    __syncthreads();
    const int w = t >> 6, l = t & 63;
#pragma unroll
    for (int ri = 0; ri < 2; ++ri) {
        int i = w * 2 + ri;
        float s = 0.f, ss = 0.f;
#pragma unroll
        for (int c = 0; c < 4; ++c) { float vv = ys[i][l + c * 64]; s += vv; ss += vv * vv; }
#pragma unroll
        for (int off = 32; off; off >>= 1) { s += __shfl_xor(s, off); ss += __shfl_xor(ss, off); }
        if (l == 0) {
            float mu = s * (1.f / 256.f);
            float var = ss * (1.f / 256.f) - mu * mu;
            mus[i] = mu; rss[i] = rsqrtf(var + LNEPS);
        }
    }
    __syncthreads();
    const float gv = g2[t], bvl = b2ln[t];
#pragma unroll
    for (int i = 0; i < 8; ++i)
        out[(row0 + i) * DM + t] = (ys[i][t] - mus[i]) * rss[i] * gv + bvl;
}

extern "C" void kernel_launch(void* const* d_in, const int* in_sizes, int n_in,
                              void* d_out, int out_size, void* d_ws, size_t ws_size,
                              hipStream_t stream) {
    const float* x   = (const float*)d_in[0];
    const float* wq  = (const float*)d_in[1];  const float* bq  = (const float*)d_in[2];
    const float* wk  = (const float*)d_in[3];  const float* bk  = (const float*)d_in[4];
    const float* wv  = (const float*)d_in[5];  const float* bv  = (const float*)d_in[6];
    const float* wo  = (const float*)d_in[7];  const float* wob = (const float*)d_in[8];
    const float* w1  = (const float*)d_in[9];  const float* b1  = (const float*)d_in[10];
    const float* w2  = (const float*)d_in[11]; const float* b2  = (const float*)d_in[12];
    const float* g1  = (const float*)d_in[13]; const float* bl1 = (const float*)d_in[14];
    const float* g2  = (const float*)d_in[15]; const float* bl2 = (const float*)d_in[16];

    float* ws   = (float*)d_ws;
    float* qb   = ws + OFF_Q;
    float* kb   = ws + OFF_K;
    float* vb   = ws + OFF_V;
    float* k2b  = ws + OFF_K2;
    float* pnum = ws + OFF_PN;
    float* pden = ws + OFF_PD;
    float* ctx  = ws + OFF_CTX;
    float* o1   = ws + OFF_O1;
    float* mid  = ws + OFF_MID;
    float* out  = (float*)d_out;

    k_qkv<<<dim3(512), dim3(256), 0, stream>>>(x, wq, bq, wk, bk, wv, bv, qb, kb, vb);
    k_k2<<<dim3(256), dim3(256), 0, stream>>>(kb, k2b);
    k_attn<<<dim3(1024), dim3(256), 0, stream>>>(qb, kb, vb, k2b, pnum, pden);
    k_combine<<<dim3(2048), dim3(256), 0, stream>>>(pnum, pden, ctx);
    k_wo_ln1<<<dim3(512), dim3(256), 0, stream>>>(ctx, wo, wob, x, g1, bl1, o1);
    k_ffn1<<<dim3(2048), dim3(256), 0, stream>>>(o1, w1, b1, mid);
    k_ffn2_ln2<<<dim3(1024), dim3(256), 0, stream>>>(mid, w2, b2, o1, g2, bl2, out);
}

// Round 2
// 497.724 us; speedup vs baseline: 1.6436x; 1.6436x over previous
//
#include <hip/hip_runtime.h>
#include <hip/hip_bf16.h>

#define BQ   4
#define SQL  2048
#define DM   256
#define NH   8
#define DEP  32
#define DFF_ 1024
#define LNEPS 1e-6f
#define NLOG2E_H (-0.72134752f)   /* -0.5*log2(e) */
#define LOG2E    (1.44269504f)

// ---- workspace layout (float offsets) ----
#define OFF_Q   0u
#define OFF_K   2097152u
#define OFF_V   4194304u
#define OFF_HK  6291456u             // 65536
#define OFF_CTX 15007744u
#define OFF_O1  17104896u
#define OFF_MID 0u                   // aliases q/k/v (dead by then)

typedef float  f32x16 __attribute__((ext_vector_type(16)));
typedef short  bf16x8 __attribute__((ext_vector_type(8)));
typedef int    i32x4  __attribute__((ext_vector_type(4)));
typedef int    i32x2  __attribute__((ext_vector_type(2)));

static __device__ __forceinline__ unsigned short bfu(float f){
    __hip_bfloat16 h = __float2bfloat16(f);
    return *reinterpret_cast<unsigned short*>(&h);
}
static __device__ __forceinline__ unsigned pk2(float a, float b){
    return (unsigned)bfu(a) | ((unsigned)bfu(b) << 16);
}
static __device__ __forceinline__ bf16x8 pack8(float4 a, float4 b){
    i32x4 t; t[0]=pk2(a.x,a.y); t[1]=pk2(a.z,a.w); t[2]=pk2(b.x,b.y); t[3]=pk2(b.z,b.w);
    return __builtin_bit_cast(bf16x8, t);
}

// ---------------- QKV projection: q/k/v = x @ W + b ----------------
__global__ __launch_bounds__(256) void k_qkv(
    const float* __restrict__ x,
    const float* __restrict__ wq, const float* __restrict__ bq,
    const float* __restrict__ wk, const float* __restrict__ bk,
    const float* __restrict__ wv, const float* __restrict__ bv,
    float* __restrict__ q, float* __restrict__ k, float* __restrict__ v)
{
    __shared__ float xs[16][256];
    const int t = threadIdx.x;
    const int row0 = blockIdx.x * 16;
    {
        const float4* src = (const float4*)(x + row0 * DM);
        float4* dst = (float4*)xs;
#pragma unroll
        for (int i = 0; i < 4; ++i) dst[i * 256 + t] = src[i * 256 + t];
    }
    __syncthreads();
    float aq[16], ak[16], av[16];
#pragma unroll
    for (int i = 0; i < 16; ++i) { aq[i] = 0.f; ak[i] = 0.f; av[i] = 0.f; }
    for (int kk = 0; kk < 256; kk += 4) {
        float q0 = wq[(kk + 0) * DM + t], q1 = wq[(kk + 1) * DM + t];
        float q2 = wq[(kk + 2) * DM + t], q3 = wq[(kk + 3) * DM + t];
        float k0 = wk[(kk + 0) * DM + t], k1 = wk[(kk + 1) * DM + t];
        float k2v = wk[(kk + 2) * DM + t], k3 = wk[(kk + 3) * DM + t];
        float v0 = wv[(kk + 0) * DM + t], v1 = wv[(kk + 1) * DM + t];
        float v2 = wv[(kk + 2) * DM + t], v3 = wv[(kk + 3) * DM + t];
#pragma unroll
        for (int i = 0; i < 16; ++i) {
            float4 xv = *(const float4*)&xs[i][kk];
            aq[i] = fmaf(xv.x, q0, fmaf(xv.y, q1, fmaf(xv.z, q2, fmaf(xv.w, q3, aq[i]))));
            ak[i] = fmaf(xv.x, k0, fmaf(xv.y, k1, fmaf(xv.z, k2v, fmaf(xv.w, k3, ak[i]))));
            av[i] = fmaf(xv.x, v0, fmaf(xv.y, v1, fmaf(xv.z, v2, fmaf(xv.w, v3, av[i]))));
        }
    }
    const float bqv = bq[t], bkv = bk[t], bvv = bv[t];
#pragma unroll
    for (int i = 0; i < 16; ++i) {
        q[(row0 + i) * DM + t] = aq[i] + bqv;
        k[(row0 + i) * DM + t] = ak[i] + bkv;
        v[(row0 + i) * DM + t] = av[i] + bvv;
    }
}

// ---------------- hk[bh*S+s] = -0.5*log2e * sum_d k^2 ----------------
__global__ __launch_bounds__(256) void k_hk(const float* __restrict__ k,
                                            float* __restrict__ hk)
{
    const int gid = blockIdx.x * 256 + threadIdx.x;   // 0..65535
    const int bh = gid >> 11, s = gid & 2047;
    const int b = bh >> 3, h = bh & 7;
    const float4* src = (const float4*)(k + ((size_t)(b * SQL + s)) * DM + h * DEP);
    float acc = 0.f;
#pragma unroll
    for (int ii = 0; ii < 8; ++ii) {
        float4 a = src[ii];
        acc += a.x * a.x + a.y * a.y + a.z * a.z + a.w * a.w;
    }
    hk[gid] = NLOG2E_H * acc;
}

// ---------------- MFMA attention ----------------
// S^T = mfma(K, Q^T) per 32-key x 32-q tile; lane column = one q.
// w = exp2(L2E * exp2(L2E*(dot + hq + hk))) in (1, e] -> no max tracking.
// PV uses lane-local permuted key order (A = own score regs, B = V^T b64 pairs).
__global__ __launch_bounds__(256) void k_attn(
    const float* __restrict__ q, const float* __restrict__ k,
    const float* __restrict__ v, const float* __restrict__ hk,
    float* __restrict__ ctx)
{
    __shared__ __align__(16) char kls[4096];   // K tile [64 key][32 d] bf16, group-swizzled
    __shared__ __align__(16) char vtl[4096];   // V^T tile [32 d][64 key] bf16, xor-swizzled
    __shared__ __align__(16) float hks[64];
    __shared__ __align__(16) float invs[128];

    const int t = threadIdx.x;
    const int lane = t & 63;
    const int wv = t >> 6;
    const int lo = lane & 31;
    const int hi = lane >> 5;

    const int bid = blockIdx.x;
    const int qchunk = bid & 15;
    const int bh = bid >> 4;
    const int b = bh >> 3, h = bh & 7;

    const int qrow = qchunk * 128 + wv * 32 + lo;
    const float* qp = q + ((size_t)(b * SQL + qrow)) * DM + h * DEP;

    bf16x8 qf[2]; float q2p = 0.f;
#pragma unroll
    for (int dh = 0; dh < 2; ++dh) {
        float4 a  = *(const float4*)(qp + dh * 16 + hi * 8);
        float4 bb = *(const float4*)(qp + dh * 16 + hi * 8 + 4);
        q2p += a.x*a.x + a.y*a.y + a.z*a.z + a.w*a.w
             + bb.x*bb.x + bb.y*bb.y + bb.z*bb.z + bb.w*bb.w;
        qf[dh] = pack8(a, bb);
    }
    const float q2 = q2p + __shfl_xor(q2p, 32);
    const float hq = NLOG2E_H * q2;

    f32x16 acc = {};
    float den = 0.f;

    const int kl_key = t >> 2;        // 0..63 (tile-local staged key)
    const int kl_g   = t & 3;         // 8-float group
    const float* kbg = k + ((size_t)(b * SQL)) * DM + h * DEP;
    const float* vbg = v + ((size_t)(b * SQL)) * DM + h * DEP;

    for (int kt = 0; kt < 32; ++kt) {
        const int key0 = kt * 64;
        // ---- stage K (bf16, group-swizzled) + V^T (bf16, xor-swizzled) + hk ----
        {
            const float* kr = kbg + (size_t)(key0 + kl_key) * DM + kl_g * 8;
            float4 ka = *(const float4*)kr;  float4 kb4 = *(const float4*)(kr + 4);
            const int gsw = kl_g ^ ((kl_key >> 1) & 3);
            *(bf16x8*)(kls + kl_key * 64 + gsw * 16) = pack8(ka, kb4);

            const float* vr = vbg + (size_t)(key0 + kl_key) * DM + kl_g * 8;
            float4 va = *(const float4*)vr;  float4 vb4 = *(const float4*)(vr + 4);
            float vv[8] = {va.x, va.y, va.z, va.w, vb4.x, vb4.y, vb4.z, vb4.w};
#pragma unroll
            for (int j = 0; j < 8; ++j) {
                const int d = kl_g * 8 + j;
                const int addr = d * 128 + ((kl_key * 2) ^ ((d & 7) << 4));
                *(unsigned short*)(vtl + addr) = bfu(vv[j]);
            }
            if (t < 64) hks[t] = hk[(size_t)bh * SQL + key0 + t];
        }
        __syncthreads();

#pragma unroll
        for (int h2 = 0; h2 < 2; ++h2) {
            const int kb32 = h2 * 32;
            // --- QK^T (S^T tile) ---
            const int kA = kb32 + lo;
            const char* krow = kls + kA * 64;
            const int ksw = (kA >> 1) & 3;
            bf16x8 kf0 = *(const bf16x8*)(krow + (((0 + hi) ^ ksw) << 4));
            bf16x8 kf1 = *(const bf16x8*)(krow + (((2 + hi) ^ ksw) << 4));
            f32x16 sc = {};
            sc = __builtin_amdgcn_mfma_f32_32x32x16_bf16(kf0, qf[0], sc, 0, 0, 0);
            sc = __builtin_amdgcn_mfma_f32_32x32x16_bf16(kf1, qf[1], sc, 0, 0, 0);
            // --- kernel weights ---
            float4 h0 = *(const float4*)&hks[kb32 + 4 * hi];
            float4 h1 = *(const float4*)&hks[kb32 + 8 + 4 * hi];
            float4 h2v = *(const float4*)&hks[kb32 + 16 + 4 * hi];
            float4 h3 = *(const float4*)&hks[kb32 + 24 + 4 * hi];
            float hkv[16] = {h0.x,h0.y,h0.z,h0.w, h1.x,h1.y,h1.z,h1.w,
                             h2v.x,h2v.y,h2v.z,h2v.w, h3.x,h3.y,h3.z,h3.w};
            float w[16];
#pragma unroll
            for (int r = 0; r < 16; ++r) {
                float arg = fmaf(sc[r], LOG2E, hq + hkv[r]);
                float e1  = __builtin_amdgcn_exp2f(arg);
                float ww  = __builtin_amdgcn_exp2f(e1 * LOG2E);
                den += ww;
                w[r] = ww;
            }
            // --- pack P (lane-local permuted key order) ---
            i32x4 p0; p0[0]=pk2(w[0],w[1]);  p0[1]=pk2(w[2],w[3]);
                      p0[2]=pk2(w[4],w[5]);  p0[3]=pk2(w[6],w[7]);
            i32x4 p1; p1[0]=pk2(w[8],w[9]);  p1[1]=pk2(w[10],w[11]);
                      p1[2]=pk2(w[12],w[13]); p1[3]=pk2(w[14],w[15]);
            // --- V^T B-frags (same permuted key order) ---
            const char* vrow = vtl + lo * 128;
            const int vxor = (lo & 7) << 4;
            const int o0 = (kb32 + 4 * hi) * 2;
            const int o1 = (kb32 + 16 + 4 * hi) * 2;
            i32x2 a0 = *(const i32x2*)(vrow + (o0 ^ vxor));
            i32x2 a1 = *(const i32x2*)(vrow + ((o0 + 16) ^ vxor));
            i32x2 b0 = *(const i32x2*)(vrow + (o1 ^ vxor));
            i32x2 b1 = *(const i32x2*)(vrow + ((o1 + 16) ^ vxor));
            i32x4 vb0; vb0[0]=a0[0]; vb0[1]=a0[1]; vb0[2]=a1[0]; vb0[3]=a1[1];
            i32x4 vb1; vb1[0]=b0[0]; vb1[1]=b0[1]; vb1[2]=b1[0]; vb1[3]=b1[1];
            // --- PV ---
            acc = __builtin_amdgcn_mfma_f32_32x32x16_bf16(
                __builtin_bit_cast(bf16x8, p0), __builtin_bit_cast(bf16x8, vb0), acc, 0, 0, 0);
            acc = __builtin_amdgcn_mfma_f32_32x32x16_bf16(
                __builtin_bit_cast(bf16x8, p1), __builtin_bit_cast(bf16x8, vb1), acc, 0, 0, 0);
        }
        __syncthreads();
    }

    // ---- epilogue: den across lane pairs, divide, write ctx ----
    const float dfull = den + __shfl_xor(den, 32);
    if (lane < 32) invs[wv * 32 + lo] = 1.f / dfull;
    __syncthreads();
    float4 i0 = *(const float4*)&invs[wv * 32 + 4 * hi];
    float4 i1 = *(const float4*)&invs[wv * 32 + 8 + 4 * hi];
    float4 i2 = *(const float4*)&invs[wv * 32 + 16 + 4 * hi];
    float4 i3 = *(const float4*)&invs[wv * 32 + 24 + 4 * hi];
    float iv[16] = {i0.x,i0.y,i0.z,i0.w, i1.x,i1.y,i1.z,i1.w,
                    i2.x,i2.y,i2.z,i2.w, i3.x,i3.y,i3.z,i3.w};
    float* cbase = ctx + ((size_t)(b * SQL + qchunk * 128 + wv * 32)) * DM + h * DEP + lo;
#pragma unroll
    for (int r = 0; r < 16; ++r) {
        const int qr = (r & 3) + 8 * (r >> 2) + 4 * hi;
        cbase[(size_t)qr * DM] = acc[r] * iv[r];
    }
}

// ---------------- out1 = LN(x + ctx@wo + wob) ----------------
__global__ __launch_bounds__(256) void k_wo_ln1(
    const float* __restrict__ ctx, const float* __restrict__ wo,
    const float* __restrict__ wob, const float* __restrict__ x,
    const float* __restrict__ g1, const float* __restrict__ b1,
    float* __restrict__ out1)
{
    __shared__ float cs[16][256];
    __shared__ float mus[16], rss[16];
    const int t = threadIdx.x;
    const int row0 = blockIdx.x * 16;
    {
        const float4* src = (const float4*)(ctx + row0 * DM);
        float4* dst = (float4*)cs;
#pragma unroll
        for (int i = 0; i < 4; ++i) dst[i * 256 + t] = src[i * 256 + t];
    }
    __syncthreads();
    float acc[16];
#pragma unroll
    for (int i = 0; i < 16; ++i) acc[i] = 0.f;
    for (int kk = 0; kk < 256; kk += 4) {
        float w0 = wo[(kk + 0) * DM + t], w1 = wo[(kk + 1) * DM + t];
        float w2 = wo[(kk + 2) * DM + t], w3 = wo[(kk + 3) * DM + t];
#pragma unroll
        for (int i = 0; i < 16; ++i) {
            float4 xv = *(const float4*)&cs[i][kk];
            acc[i] = fmaf(xv.x, w0, fmaf(xv.y, w1, fmaf(xv.z, w2, fmaf(xv.w, w3, acc[i]))));
        }
    }
    __syncthreads();
    const float wobv = wob[t];
#pragma unroll
    for (int i = 0; i < 16; ++i) {
        float y = acc[i] + wobv + x[(row0 + i) * DM + t];
        cs[i][t] = y;
    }
    __syncthreads();
    const int w = t >> 6, l = t & 63;
#pragma unroll
    for (int ri = 0; ri < 4; ++ri) {
        int i = w * 4 + ri;
        float s = 0.f, ss = 0.f;
#pragma unroll
        for (int c = 0; c < 4; ++c) { float vv = cs[i][l + c * 64]; s += vv; ss += vv * vv; }
#pragma unroll
        for (int off = 32; off; off >>= 1) { s += __shfl_xor(s, off); ss += __shfl_xor(ss, off); }
        if (l == 0) {
            float mu = s * (1.f / 256.f);
            float var = ss * (1.f / 256.f) - mu * mu;
            mus[i] = mu; rss[i] = rsqrtf(var + LNEPS);
        }
    }
    __syncthreads();
    const float gv = g1[t], bv = b1[t];
#pragma unroll
    for (int i = 0; i < 16; ++i)
        out1[(row0 + i) * DM + t] = (cs[i][t] - mus[i]) * rss[i] * gv + bv;
}

// ---------------- mid = relu(out1 @ W1 + b1) ----------------
__global__ __launch_bounds__(256) void k_ffn1(
    const float* __restrict__ out1, const float* __restrict__ w1,
    const float* __restrict__ b1f, float* __restrict__ mid)
{
    __shared__ float cs[16][256];
    const int t = threadIdx.x;
    const int rt = blockIdx.x >> 2;
    const int cg = blockIdx.x & 3;
    const int row0 = rt * 16;
    const int col = cg * 256 + t;
    {
        const float4* src = (const float4*)(out1 + row0 * DM);
        float4* dst = (float4*)cs;
#pragma unroll
        for (int i = 0; i < 4; ++i) dst[i * 256 + t] = src[i * 256 + t];
    }
    __syncthreads();
    float acc[16];
#pragma unroll
    for (int i = 0; i < 16; ++i) acc[i] = 0.f;
    for (int kk = 0; kk < 256; kk += 4) {
        float w0 = w1[(kk + 0) * DFF_ + col], w1v = w1[(kk + 1) * DFF_ + col];
        float w2 = w1[(kk + 2) * DFF_ + col], w3 = w1[(kk + 3) * DFF_ + col];
#pragma unroll
        for (int i = 0; i < 16; ++i) {
            float4 xv = *(const float4*)&cs[i][kk];
            acc[i] = fmaf(xv.x, w0, fmaf(xv.y, w1v, fmaf(xv.z, w2, fmaf(xv.w, w3, acc[i]))));
        }
    }
    const float bv = b1f[col];
#pragma unroll
    for (int i = 0; i < 16; ++i)
        mid[(row0 + i) * DFF_ + col] = fmaxf(acc[i] + bv, 0.f);
}

// ---------------- out = LN(out1 + mid @ W2 + b2) ----------------
__global__ __launch_bounds__(256) void k_ffn2_ln2(
    const float* __restrict__ mid, const float* __restrict__ w2,
    const float* __restrict__ b2f, const float* __restrict__ out1,
    const float* __restrict__ g2, const float* __restrict__ b2ln,
    float* __restrict__ out)
{
    __shared__ float ms[8][1024];
    __shared__ float ys[8][256];
    __shared__ float mus[8], rss[8];
    const int t = threadIdx.x;
    const int row0 = blockIdx.x * 8;
    {
        const float4* src = (const float4*)(mid + row0 * DFF_);
        float4* dst = (float4*)ms;
#pragma unroll
        for (int i = 0; i < 8; ++i) dst[i * 256 + t] = src[i * 256 + t];
    }
    __syncthreads();
    float acc[8];
#pragma unroll
    for (int i = 0; i < 8; ++i) acc[i] = 0.f;
    for (int kk = 0; kk < 1024; kk += 4) {
        float w0 = w2[(kk + 0) * DM + t], w1v = w2[(kk + 1) * DM + t];
        float w2v = w2[(kk + 2) * DM + t], w3 = w2[(kk + 3) * DM + t];
#pragma unroll
        for (int i = 0; i < 8; ++i) {
            float4 xv = *(const float4*)&ms[i][kk];
            acc[i] = fmaf(xv.x, w0, fmaf(xv.y, w1v, fmaf(xv.z, w2v, fmaf(xv.w, w3, acc[i]))));
        }
    }
    const float bv = b2f[t];
#pragma unroll
    for (int i = 0; i < 8; ++i) {
        float y = acc[i] + bv + out1[(row0 + i) * DM + t];
        ys[i][t] = y;
    }
    __syncthreads();
    const int w = t >> 6, l = t & 63;
#pragma unroll
    for (int ri = 0; ri < 2; ++ri) {
        int i = w * 2 + ri;
        float s = 0.f, ss = 0.f;
#pragma unroll
        for (int c = 0; c < 4; ++c) { float vv = ys[i][l + c * 64]; s += vv; ss += vv * vv; }
#pragma unroll
        for (int off = 32; off; off >>= 1) { s += __shfl_xor(s, off); ss += __shfl_xor(ss, off); }
        if (l == 0) {
            float mu = s * (1.f / 256.f);
            float var = ss * (1.f / 256.f) - mu * mu;
            mus[i] = mu; rss[i] = rsqrtf(var + LNEPS);
        }
    }
    __syncthreads();
    const float gv = g2[t], bvl = b2ln[t];
#pragma unroll
    for (int i = 0; i < 8; ++i)
        out[(row0 + i) * DM + t] = (ys[i][t] - mus[i]) * rss[i] * gv + bvl;
}

extern "C" void kernel_launch(void* const* d_in, const int* in_sizes, int n_in,
                              void* d_out, int out_size, void* d_ws, size_t ws_size,
                              hipStream_t stream) {
    const float* x   = (const float*)d_in[0];
    const float* wq  = (const float*)d_in[1];  const float* bq  = (const float*)d_in[2];
    const float* wk  = (const float*)d_in[3];  const float* bk  = (const float*)d_in[4];
    const float* wv  = (const float*)d_in[5];  const float* bv  = (const float*)d_in[6];
    const float* wo  = (const float*)d_in[7];  const float* wob = (const float*)d_in[8];
    const float* w1  = (const float*)d_in[9];  const float* b1  = (const float*)d_in[10];
    const float* w2  = (const float*)d_in[11]; const float* b2  = (const float*)d_in[12];
    const float* g1  = (const float*)d_in[13]; const float* bl1 = (const float*)d_in[14];
    const float* g2  = (const float*)d_in[15]; const float* bl2 = (const float*)d_in[16];

    float* ws   = (float*)d_ws;
    float* qb   = ws + OFF_Q;
    float* kb   = ws + OFF_K;
    float* vb   = ws + OFF_V;
    float* hkb  = ws + OFF_HK;
    float* ctx  = ws + OFF_CTX;
    float* o1   = ws + OFF_O1;
    float* mid  = ws + OFF_MID;
    float* out  = (float*)d_out;

    k_qkv<<<dim3(512), dim3(256), 0, stream>>>(x, wq, bq, wk, bk, wv, bv, qb, kb, vb);
    k_hk<<<dim3(256), dim3(256), 0, stream>>>(kb, hkb);
    k_attn<<<dim3(512), dim3(256), 0, stream>>>(qb, kb, vb, hkb, ctx);
    k_wo_ln1<<<dim3(512), dim3(256), 0, stream>>>(ctx, wo, wob, x, g1, bl1, o1);
    k_ffn1<<<dim3(2048), dim3(256), 0, stream>>>(o1, w1, b1, mid);
    k_ffn2_ln2<<<dim3(1024), dim3(256), 0, stream>>>(mid, w2, b2, o1, g2, bl2, out);
}

// Round 3
// 227.606 us; speedup vs baseline: 3.5941x; 2.1868x over previous
//
#include <hip/hip_runtime.h>
#include <hip/hip_bf16.h>

#define SQL  2048
#define DM   256
#define LNEPS 1e-6f
#define NLOG2E_H (-0.72134752f)   /* -0.5*log2(e) */
#define LOG2E    (1.44269504f)

// ---- workspace layout (byte offsets) ----
#define B_XB    (0ull)            // 4 MB  x bf16 [8192][256]
#define B_QB    (4ull<<20)        // 4 MB  q bf16 [bh][s][32]
#define B_KB    (8ull<<20)
#define B_VB    (12ull<<20)
#define B_CTX   (16ull<<20)       // 4 MB  ctx bf16 [8192][256]
#define B_O1B   (20ull<<20)       // 4 MB  out1 bf16
#define B_MID   (24ull<<20)       // 16 MB mid bf16 [8192][1024]
#define B_WQKVT (40ull<<20)       // 384 KB bf16 [768][256]
#define B_WOT   (41ull<<20)       // 128 KB bf16 [256][256]
#define B_W1T   (42ull<<20)       // 512 KB bf16 [1024][256]
#define B_W2T   (43ull<<20)       // 512 KB bf16 [256][1024]
#define B_BQKV  (44ull<<20)       // 3 KB f32 [768]
#define B_HQ    (45ull<<20)       // 256 KB f32 [65536]
#define B_HK    (46ull<<20)       // 256 KB
#define B_C1    (47ull<<20)       // 8 MB f32
#define B_O1F   (55ull<<20)       // 8 MB f32
#define B_C2    (63ull<<20)       // 8 MB f32 (ends 71 MB)

typedef float  f32x16 __attribute__((ext_vector_type(16)));
typedef short  bf16x8 __attribute__((ext_vector_type(8)));
typedef int    i32x4  __attribute__((ext_vector_type(4)));
typedef int    i32x2  __attribute__((ext_vector_type(2)));

static __device__ __forceinline__ unsigned short bfu(float f){
    __hip_bfloat16 h = __float2bfloat16(f);
    return *reinterpret_cast<unsigned short*>(&h);
}
static __device__ __forceinline__ unsigned pk2(float a, float b){
    return (unsigned)bfu(a) | ((unsigned)bfu(b) << 16);
}
static __device__ __forceinline__ void glds16(const void* g, void* l){
    __builtin_amdgcn_global_load_lds((const __attribute__((address_space(1))) unsigned int*)g,
                                     (__attribute__((address_space(3))) unsigned int*)l, 16, 0, 0);
}

// ---------------- weight transpose+cvt: W[K][N] f32 -> Wt[N][K] bf16 ----------------
__global__ __launch_bounds__(256) void k_pack(const float* __restrict__ W,
                                              unsigned short* __restrict__ Wt,
                                              int K, int N)
{
    __shared__ float tile[32][33];
    const int t = threadIdx.x;
    const int tx = t & 31, ty = t >> 5;
    const int kb = blockIdx.x * 32, nb = blockIdx.y * 32;
#pragma unroll
    for (int i = 0; i < 32; i += 8) tile[ty + i][tx] = W[(size_t)(kb + ty + i) * N + nb + tx];
    __syncthreads();
#pragma unroll
    for (int i = 0; i < 32; i += 8) Wt[(size_t)(nb + ty + i) * K + kb + tx] = bfu(tile[tx][ty + i]);
}

__global__ __launch_bounds__(256) void k_packb(const float* __restrict__ bq,
                                               const float* __restrict__ bk,
                                               const float* __restrict__ bv,
                                               float* __restrict__ bqkv)
{
    const int wb = blockIdx.x;
    const float* s = (wb == 0) ? bq : (wb == 1 ? bk : bv);
    bqkv[wb * 256 + threadIdx.x] = s[threadIdx.x];
}

// ---------------- x f32 -> bf16 ----------------
__global__ __launch_bounds__(256) void k_xb(const float* __restrict__ x,
                                            unsigned short* __restrict__ xb)
{
    const int i = blockIdx.x * 256 + threadIdx.x;   // 4 elems each
    float4 v = ((const float4*)x)[i];
    ushort4 o; o.x = bfu(v.x); o.y = bfu(v.y); o.z = bfu(v.z); o.w = bfu(v.w);
    ((ushort4*)xb)[i] = o;
}

// ---------------- QKV MFMA GEMM: xb[8192][256] @ wqkvT -> q/k/v bf16 [bh][s][32] ----------------
__global__ __launch_bounds__(256, 2) void k_qkv(
    const unsigned short* __restrict__ A, const unsigned short* __restrict__ Bt,
    const float* __restrict__ bias,
    unsigned short* __restrict__ qb, unsigned short* __restrict__ kb,
    unsigned short* __restrict__ vb)
{
    __shared__ __align__(16) char As[16384];
    __shared__ __align__(16) char Bs[16384];
    const int t = threadIdx.x;
    const int lane = t & 63, w = t >> 6;
    const int lo = lane & 31, hi = lane >> 5;
    const int row0 = blockIdx.x * 128;
    const int col0 = blockIdx.y * 128;
    f32x16 acc[2][2] = {};
    const int gS = lane & 7;

    for (int kt = 0; kt < 4; ++kt) {
        const int k0 = kt * 64;
#pragma unroll
        for (int i = 0; i < 4; ++i) {
            const int r = w * 32 + i * 8 + (lane >> 3);
            glds16((const char*)(A  + (size_t)(row0 + r) * 256 + k0) + ((gS ^ (r & 7)) << 4),
                   As + w * 4096 + i * 1024 + lane * 16);
            glds16((const char*)(Bt + (size_t)(col0 + r) * 256 + k0) + ((gS ^ (r & 7)) << 4),
                   Bs + w * 4096 + i * 1024 + lane * 16);
        }
        __syncthreads();
        const int rA = (w >> 1) * 64 + lo;
        const int rB = (w & 1) * 64 + lo;
#pragma unroll
        for (int s = 0; s < 4; ++s) {
            const int g = s * 2 + hi;
            bf16x8 fa0 = *(const bf16x8*)(As + rA * 128 + ((g ^ (rA & 7)) << 4));
            bf16x8 fa1 = *(const bf16x8*)(As + (rA + 32) * 128 + ((g ^ (rA & 7)) << 4));
            bf16x8 fb0 = *(const bf16x8*)(Bs + rB * 128 + ((g ^ (rB & 7)) << 4));
            bf16x8 fb1 = *(const bf16x8*)(Bs + (rB + 32) * 128 + ((g ^ (rB & 7)) << 4));
            acc[0][0] = __builtin_amdgcn_mfma_f32_32x32x16_bf16(fa0, fb0, acc[0][0], 0, 0, 0);
            acc[0][1] = __builtin_amdgcn_mfma_f32_32x32x16_bf16(fa0, fb1, acc[0][1], 0, 0, 0);
            acc[1][0] = __builtin_amdgcn_mfma_f32_32x32x16_bf16(fa1, fb0, acc[1][0], 0, 0, 0);
            acc[1][1] = __builtin_amdgcn_mfma_f32_32x32x16_bf16(fa1, fb1, acc[1][1], 0, 0, 0);
        }
        __syncthreads();
    }
#pragma unroll
    for (int m = 0; m < 2; ++m)
#pragma unroll
    for (int n = 0; n < 2; ++n) {
        const int c0 = col0 + (w & 1) * 64 + n * 32;
        const int which = c0 >> 8, h = (c0 >> 5) & 7;
        unsigned short* dst = (which == 0) ? qb : (which == 1 ? kb : vb);
        const float bv = bias[c0 + lo];
#pragma unroll
        for (int r = 0; r < 16; ++r) {
            const int gr = row0 + (w >> 1) * 64 + m * 32 + (r & 3) + 8 * (r >> 2) + 4 * hi;
            const int b = gr >> 11, s = gr & 2047;
            dst[(((size_t)(b * 8 + h)) * SQL + s) * 32 + lo] = bfu(acc[m][n][r] + bv);
        }
    }
}

// ---------------- hq/hk from bf16 q/k ----------------
__global__ __launch_bounds__(256) void k_h2(const unsigned short* __restrict__ qb,
                                            const unsigned short* __restrict__ kb,
                                            float* __restrict__ hq, float* __restrict__ hk)
{
    const int gid = blockIdx.x * 256 + threadIdx.x;
    const unsigned short* qp = qb + (size_t)gid * 32;
    const unsigned short* kp = kb + (size_t)gid * 32;
    float sq = 0.f, sk = 0.f;
#pragma unroll
    for (int i = 0; i < 4; ++i) {
        i32x4 qv = *(const i32x4*)(qp + i * 8);
        i32x4 kv = *(const i32x4*)(kp + i * 8);
#pragma unroll
        for (int j = 0; j < 4; ++j) {
            unsigned int qw = (unsigned int)qv[j], kw = (unsigned int)kv[j];
            float a = __builtin_bit_cast(float, qw << 16);
            float c = __builtin_bit_cast(float, qw & 0xffff0000u);
            float d = __builtin_bit_cast(float, kw << 16);
            float e = __builtin_bit_cast(float, kw & 0xffff0000u);
            sq += a * a + c * c; sk += d * d + e * e;
        }
    }
    hq[gid] = NLOG2E_H * sq;
    hk[gid] = NLOG2E_H * sk;
}

// ---------------- MFMA attention (bf16 inputs) ----------------
__global__ __launch_bounds__(256) void k_attn(
    const unsigned short* __restrict__ qg, const unsigned short* __restrict__ kg,
    const unsigned short* __restrict__ vg, const float* __restrict__ hq,
    const float* __restrict__ hk, unsigned short* __restrict__ ctxb)
{
    __shared__ __align__(16) char kls[4096];
    __shared__ __align__(16) char vtl[4096];
    __shared__ __align__(16) float hks[64];
    __shared__ __align__(16) float invs[128];

    const int t = threadIdx.x;
    const int lane = t & 63;
    const int wv_ = t >> 6;
    const int lo = lane & 31;
    const int hi = lane >> 5;

    const int bid = blockIdx.x;
    const int qchunk = bid & 15;
    const int bh = bid >> 4;
    const int b = bh >> 3, h = bh & 7;

    const int qrow = qchunk * 128 + wv_ * 32 + lo;
    const unsigned short* qp = qg + ((size_t)bh * SQL + qrow) * 32;
    bf16x8 qf[2];
    qf[0] = *(const bf16x8*)(qp + hi * 8);
    qf[1] = *(const bf16x8*)(qp + 16 + hi * 8);
    const float hqv = hq[(size_t)bh * SQL + qrow];

    f32x16 acc = {};
    float den = 0.f;

    const int vr_key = t >> 2;
    const int vr_g   = t & 3;
    const unsigned short* kbg = kg + (size_t)bh * SQL * 32;
    const unsigned short* vbg = vg + (size_t)bh * SQL * 32;

    for (int kt = 0; kt < 32; ++kt) {
        const int key0 = kt * 64;
        {
            const int r = (wv_ << 4) + (lane >> 2);
            const int gl = lane & 3;
            glds16((const char*)(kbg + (size_t)(key0 + r) * 32) + ((gl ^ ((r >> 1) & 3)) << 4),
                   kls + wv_ * 1024 + lane * 16);
            const unsigned short* vr = vbg + (size_t)(key0 + vr_key) * 32 + vr_g * 8;
            i32x4 vl = *(const i32x4*)vr;
#pragma unroll
            for (int j2 = 0; j2 < 4; ++j2) {
                unsigned int wrd = (unsigned int)vl[j2];
                const int d0 = vr_g * 8 + j2 * 2;
                *(unsigned short*)(vtl + d0 * 128 + ((vr_key * 2) ^ ((d0 & 7) << 4))) = (unsigned short)(wrd & 0xffff);
                *(unsigned short*)(vtl + (d0 + 1) * 128 + ((vr_key * 2) ^ (((d0 + 1) & 7) << 4))) = (unsigned short)(wrd >> 16);
            }
            if (t < 64) hks[t] = hk[(size_t)bh * SQL + key0 + t];
        }
        __syncthreads();

#pragma unroll
        for (int h2 = 0; h2 < 2; ++h2) {
            const int kb32 = h2 * 32;
            const int kA = kb32 + lo;
            const char* krow = kls + kA * 64;
            const int ksw = (kA >> 1) & 3;
            bf16x8 kf0 = *(const bf16x8*)(krow + (((0 + hi) ^ ksw) << 4));
            bf16x8 kf1 = *(const bf16x8*)(krow + (((2 + hi) ^ ksw) << 4));
            f32x16 sc = {};
            sc = __builtin_amdgcn_mfma_f32_32x32x16_bf16(kf0, qf[0], sc, 0, 0, 0);
            sc = __builtin_amdgcn_mfma_f32_32x32x16_bf16(kf1, qf[1], sc, 0, 0, 0);
            float4 h0 = *(const float4*)&hks[kb32 + 4 * hi];
            float4 h1 = *(const float4*)&hks[kb32 + 8 + 4 * hi];
            float4 h2v = *(const float4*)&hks[kb32 + 16 + 4 * hi];
            float4 h3 = *(const float4*)&hks[kb32 + 24 + 4 * hi];
            float hkv[16] = {h0.x,h0.y,h0.z,h0.w, h1.x,h1.y,h1.z,h1.w,
                             h2v.x,h2v.y,h2v.z,h2v.w, h3.x,h3.y,h3.z,h3.w};
            float w[16];
#pragma unroll
            for (int r = 0; r < 16; ++r) {
                float arg = fmaf(sc[r], LOG2E, hqv + hkv[r]);
                float e1  = __builtin_amdgcn_exp2f(arg);
                float ww  = __builtin_amdgcn_exp2f(e1 * LOG2E);
                den += ww;
                w[r] = ww;
            }
            i32x4 p0; p0[0]=pk2(w[0],w[1]);  p0[1]=pk2(w[2],w[3]);
                      p0[2]=pk2(w[4],w[5]);  p0[3]=pk2(w[6],w[7]);
            i32x4 p1; p1[0]=pk2(w[8],w[9]);  p1[1]=pk2(w[10],w[11]);
                      p1[2]=pk2(w[12],w[13]); p1[3]=pk2(w[14],w[15]);
            const char* vrow = vtl + lo * 128;
            const int vxor = (lo & 7) << 4;
            const int o0 = (kb32 + 4 * hi) * 2;
            const int o1 = (kb32 + 16 + 4 * hi) * 2;
            i32x2 a0 = *(const i32x2*)(vrow + (o0 ^ vxor));
            i32x2 a1 = *(const i32x2*)(vrow + ((o0 + 16) ^ vxor));
            i32x2 b0 = *(const i32x2*)(vrow + (o1 ^ vxor));
            i32x2 b1 = *(const i32x2*)(vrow + ((o1 + 16) ^ vxor));
            i32x4 vb0; vb0[0]=a0[0]; vb0[1]=a0[1]; vb0[2]=a1[0]; vb0[3]=a1[1];
            i32x4 vb1; vb1[0]=b0[0]; vb1[1]=b0[1]; vb1[2]=b1[0]; vb1[3]=b1[1];
            acc = __builtin_amdgcn_mfma_f32_32x32x16_bf16(
                __builtin_bit_cast(bf16x8, p0), __builtin_bit_cast(bf16x8, vb0), acc, 0, 0, 0);
            acc = __builtin_amdgcn_mfma_f32_32x32x16_bf16(
                __builtin_bit_cast(bf16x8, p1), __builtin_bit_cast(bf16x8, vb1), acc, 0, 0, 0);
        }
        __syncthreads();
    }

    const float dfull = den + __shfl_xor(den, 32);
    if (lane < 32) invs[wv_ * 32 + lo] = 1.f / dfull;
    __syncthreads();
    float4 i0 = *(const float4*)&invs[wv_ * 32 + 4 * hi];
    float4 i1 = *(const float4*)&invs[wv_ * 32 + 8 + 4 * hi];
    float4 i2 = *(const float4*)&invs[wv_ * 32 + 16 + 4 * hi];
    float4 i3 = *(const float4*)&invs[wv_ * 32 + 24 + 4 * hi];
    float iv[16] = {i0.x,i0.y,i0.z,i0.w, i1.x,i1.y,i1.z,i1.w,
                    i2.x,i2.y,i2.z,i2.w, i3.x,i3.y,i3.z,i3.w};
    unsigned short* cbase = ctxb + ((size_t)(b * SQL + qchunk * 128 + wv_ * 32)) * 256 + h * 32 + lo;
#pragma unroll
    for (int r = 0; r < 16; ++r) {
        const int qr = (r & 3) + 8 * (r >> 2) + 4 * hi;
        cbase[(size_t)qr * 256] = bfu(acc[r] * iv[r]);
    }
}

// ---------------- generic MFMA GEMM: A[M][K]bf16 @ Bt[N][K]bf16 ----------------
template<int KDIM, int NFULL, int RELU, int RESID, int OUTF, int OUTB>
__global__ __launch_bounds__(256, 2) void k_gemm(
    const unsigned short* __restrict__ A, const unsigned short* __restrict__ Bt,
    const float* __restrict__ bias, const float* __restrict__ resid,
    float* __restrict__ outf, unsigned short* __restrict__ outb)
{
    __shared__ __align__(16) char As[16384];
    __shared__ __align__(16) char Bs[16384];
    const int t = threadIdx.x;
    const int lane = t & 63, w = t >> 6;
    const int lo = lane & 31, hi = lane >> 5;
    const int row0 = blockIdx.x * 128;
    const int col0 = blockIdx.y * 128;
    f32x16 acc[2][2] = {};
    const int gS = lane & 7;

    for (int kt = 0; kt < KDIM / 64; ++kt) {
        const int k0 = kt * 64;
#pragma unroll
        for (int i = 0; i < 4; ++i) {
            const int r = w * 32 + i * 8 + (lane >> 3);
            glds16((const char*)(A  + (size_t)(row0 + r) * KDIM + k0) + ((gS ^ (r & 7)) << 4),
                   As + w * 4096 + i * 1024 + lane * 16);
            glds16((const char*)(Bt + (size_t)(col0 + r) * KDIM + k0) + ((gS ^ (r & 7)) << 4),
                   Bs + w * 4096 + i * 1024 + lane * 16);
        }
        __syncthreads();
        const int rA = (w >> 1) * 64 + lo;
        const int rB = (w & 1) * 64 + lo;
#pragma unroll
        for (int s = 0; s < 4; ++s) {
            const int g = s * 2 + hi;
            bf16x8 fa0 = *(const bf16x8*)(As + rA * 128 + ((g ^ (rA & 7)) << 4));
            bf16x8 fa1 = *(const bf16x8*)(As + (rA + 32) * 128 + ((g ^ (rA & 7)) << 4));
            bf16x8 fb0 = *(const bf16x8*)(Bs + rB * 128 + ((g ^ (rB & 7)) << 4));
            bf16x8 fb1 = *(const bf16x8*)(Bs + (rB + 32) * 128 + ((g ^ (rB & 7)) << 4));
            acc[0][0] = __builtin_amdgcn_mfma_f32_32x32x16_bf16(fa0, fb0, acc[0][0], 0, 0, 0);
            acc[0][1] = __builtin_amdgcn_mfma_f32_32x32x16_bf16(fa0, fb1, acc[0][1], 0, 0, 0);
            acc[1][0] = __builtin_amdgcn_mfma_f32_32x32x16_bf16(fa1, fb0, acc[1][0], 0, 0, 0);
            acc[1][1] = __builtin_amdgcn_mfma_f32_32x32x16_bf16(fa1, fb1, acc[1][1], 0, 0, 0);
        }
        __syncthreads();
    }
#pragma unroll
    for (int m = 0; m < 2; ++m)
#pragma unroll
    for (int n = 0; n < 2; ++n) {
        const int c0 = col0 + (w & 1) * 64 + n * 32;
        const float bv = bias[c0 + lo];
#pragma unroll
        for (int r = 0; r < 16; ++r) {
            const int gr = row0 + (w >> 1) * 64 + m * 32 + (r & 3) + 8 * (r >> 2) + 4 * hi;
            float vv = acc[m][n][r] + bv;
            if (RESID) vv += resid[(size_t)gr * NFULL + c0 + lo];
            if (RELU)  vv = fmaxf(vv, 0.f);
            if (OUTF)  outf[(size_t)gr * NFULL + c0 + lo] = vv;
            if (OUTB)  outb[(size_t)gr * NFULL + c0 + lo] = bfu(vv);
        }
    }
}

// ---------------- LayerNorm: 1 wave per row of 256 ----------------
template<int DUAL>
__global__ __launch_bounds__(256) void k_ln(const float* __restrict__ in,
                                            const float* __restrict__ g,
                                            const float* __restrict__ bt,
                                            float* __restrict__ outf,
                                            unsigned short* __restrict__ outb)
{
    const int row = blockIdx.x * 4 + (threadIdx.x >> 6);
    const int lane = threadIdx.x & 63;
    const float4 v = ((const float4*)(in + (size_t)row * 256))[lane];
    float s  = v.x + v.y + v.z + v.w;
    float ss = v.x * v.x + v.y * v.y + v.z * v.z + v.w * v.w;
#pragma unroll
    for (int off = 32; off; off >>= 1) { s += __shfl_xor(s, off); ss += __shfl_xor(ss, off); }
    const float mu = s * (1.f / 256.f);
    const float rstd = rsqrtf(ss * (1.f / 256.f) - mu * mu + LNEPS);
    const float4 gg = ((const float4*)g)[lane];
    const float4 bb = ((const float4*)bt)[lane];
    float4 o;
    o.x = (v.x - mu) * rstd * gg.x + bb.x;
    o.y = (v.y - mu) * rstd * gg.y + bb.y;
    o.z = (v.z - mu) * rstd * gg.z + bb.z;
    o.w = (v.w - mu) * rstd * gg.w + bb.w;
    ((float4*)(outf + (size_t)row * 256))[lane] = o;
    if (DUAL) {
        ushort4 ob; ob.x = bfu(o.x); ob.y = bfu(o.y); ob.z = bfu(o.z); ob.w = bfu(o.w);
        ((ushort4*)(outb + (size_t)row * 256))[lane] = ob;
    }
}

extern "C" void kernel_launch(void* const* d_in, const int* in_sizes, int n_in,
                              void* d_out, int out_size, void* d_ws, size_t ws_size,
                              hipStream_t stream) {
    const float* x   = (const float*)d_in[0];
    const float* wq  = (const float*)d_in[1];  const float* bq  = (const float*)d_in[2];
    const float* wk  = (const float*)d_in[3];  const float* bk  = (const float*)d_in[4];
    const float* wv  = (const float*)d_in[5];  const float* bv  = (const float*)d_in[6];
    const float* wo  = (const float*)d_in[7];  const float* wob = (const float*)d_in[8];
    const float* w1  = (const float*)d_in[9];  const float* b1  = (const float*)d_in[10];
    const float* w2  = (const float*)d_in[11]; const float* b2  = (const float*)d_in[12];
    const float* g1  = (const float*)d_in[13]; const float* bl1 = (const float*)d_in[14];
    const float* g2  = (const float*)d_in[15]; const float* bl2 = (const float*)d_in[16];

    char* ws = (char*)d_ws;
    unsigned short* xb    = (unsigned short*)(ws + B_XB);
    unsigned short* qb    = (unsigned short*)(ws + B_QB);
    unsigned short* kbuf  = (unsigned short*)(ws + B_KB);
    unsigned short* vbuf  = (unsigned short*)(ws + B_VB);
    unsigned short* ctxb  = (unsigned short*)(ws + B_CTX);
    unsigned short* o1b   = (unsigned short*)(ws + B_O1B);
    unsigned short* mid   = (unsigned short*)(ws + B_MID);
    unsigned short* wqkvT = (unsigned short*)(ws + B_WQKVT);
    unsigned short* woT   = (unsigned short*)(ws + B_WOT);
    unsigned short* w1T   = (unsigned short*)(ws + B_W1T);
    unsigned short* w2T   = (unsigned short*)(ws + B_W2T);
    float* bqkv = (float*)(ws + B_BQKV);
    float* hqb  = (float*)(ws + B_HQ);
    float* hkb  = (float*)(ws + B_HK);
    float* c1   = (float*)(ws + B_C1);
    float* o1f  = (float*)(ws + B_O1F);
    float* c2   = (float*)(ws + B_C2);
    float* out  = (float*)d_out;

    // weight packing
    k_pack<<<dim3(8, 8),  dim3(256), 0, stream>>>(wq, wqkvT,             256, 256);
    k_pack<<<dim3(8, 8),  dim3(256), 0, stream>>>(wk, wqkvT + 256 * 256, 256, 256);
    k_pack<<<dim3(8, 8),  dim3(256), 0, stream>>>(wv, wqkvT + 512 * 256, 256, 256);
    k_pack<<<dim3(8, 8),  dim3(256), 0, stream>>>(wo, woT,               256, 256);
    k_pack<<<dim3(8, 32), dim3(256), 0, stream>>>(w1, w1T,               256, 1024);
    k_pack<<<dim3(32, 8), dim3(256), 0, stream>>>(w2, w2T,               1024, 256);
    k_packb<<<dim3(3), dim3(256), 0, stream>>>(bq, bk, bv, bqkv);
    k_xb<<<dim3(2048), dim3(256), 0, stream>>>(x, xb);

    // attention path
    k_qkv<<<dim3(64, 6), dim3(256), 0, stream>>>(xb, wqkvT, bqkv, qb, kbuf, vbuf);
    k_h2<<<dim3(256), dim3(256), 0, stream>>>(qb, kbuf, hqb, hkb);
    k_attn<<<dim3(512), dim3(256), 0, stream>>>(qb, kbuf, vbuf, hqb, hkb, ctxb);
    k_gemm<256, 256, 0, 1, 1, 0><<<dim3(64, 2), dim3(256), 0, stream>>>(ctxb, woT, wob, x, c1, nullptr);
    k_ln<1><<<dim3(2048), dim3(256), 0, stream>>>(c1, g1, bl1, o1f, o1b);

    // FFN path
    k_gemm<256, 1024, 1, 0, 0, 1><<<dim3(64, 8), dim3(256), 0, stream>>>(o1b, w1T, b1, nullptr, nullptr, mid);
    k_gemm<1024, 256, 0, 1, 1, 0><<<dim3(64, 2), dim3(256), 0, stream>>>(mid, w2T, b2, o1f, c2, nullptr);
    k_ln<0><<<dim3(2048), dim3(256), 0, stream>>>(c2, g2, bl2, out, nullptr);
}

// Round 4
// 199.165 us; speedup vs baseline: 4.1074x; 1.1428x over previous
//
#include <hip/hip_runtime.h>
#include <hip/hip_bf16.h>

#define SQL  2048
#define DM   256
#define LNEPS 1e-6f
#define NLOG2E_H (-0.72134752f)   /* -0.5*log2(e) */
#define LOG2E    (1.44269504f)

// ---- workspace layout (byte offsets) ----
#define B_XB    (0ull)            // 4 MB  x bf16 [8192][256]   (c2 partials alias 0..16MB later)
#define B_QB    (4ull<<20)        // 4 MB  q bf16 [bh][s][32]
#define B_KB    (8ull<<20)        // 4 MB  k bf16 [bh][s][32]
#define B_VT    (12ull<<20)       // 4 MB  V^T bf16 [bh][32][2048], pre-swizzled
#define B_CTX   (16ull<<20)       // 4 MB  ctx bf16 [8192][256]
#define B_O1B   (20ull<<20)       // 4 MB  out1 bf16
#define B_O1F   (24ull<<20)       // 8 MB  out1 f32
#define B_MID   (32ull<<20)       // 16 MB mid bf16 [8192][1024]; ALSO c1 partials (2x8MB)
#define B_WQKVT (48ull<<20)       // 384 KB bf16 [768][256]
#define B_WOT   ((48ull<<20)+(512ull<<10))  // 128 KB
#define B_W1T   (49ull<<20)       // 512 KB bf16 [1024][256]
#define B_W2T   ((49ull<<20)+(512ull<<10))  // 512 KB bf16 [256][1024]
#define B_BQKV  (50ull<<20)       // 3 KB f32
#define B_HQ    ((50ull<<20)+(64ull<<10))   // 256 KB f32
#define B_HK    ((50ull<<20)+(320ull<<10))  // 256 KB f32
#define B_C2    (0ull)            // 16 MB f32 partials (alias xb/qb/kb/vt, dead by then)

typedef float  f32x16 __attribute__((ext_vector_type(16)));
typedef short  bf16x8 __attribute__((ext_vector_type(8)));
typedef int    i32x4  __attribute__((ext_vector_type(4)));
typedef int    i32x2  __attribute__((ext_vector_type(2)));

static __device__ __forceinline__ unsigned short bfu(float f){
    __hip_bfloat16 h = __float2bfloat16(f);
    return *reinterpret_cast<unsigned short*>(&h);
}
static __device__ __forceinline__ unsigned pk2(float a, float b){
    return (unsigned)bfu(a) | ((unsigned)bfu(b) << 16);
}
static __device__ __forceinline__ void glds16(const void* g, void* l){
    __builtin_amdgcn_global_load_lds((const __attribute__((address_space(1))) unsigned int*)g,
                                     (__attribute__((address_space(3))) unsigned int*)l, 16, 0, 0);
}

// ---------------- fused packing: weights->bf16^T, biases, x->bf16 ----------------
__global__ __launch_bounds__(256) void k_packall(
    const float* __restrict__ wq, const float* __restrict__ wk, const float* __restrict__ wv,
    const float* __restrict__ wo, const float* __restrict__ w1, const float* __restrict__ w2,
    const float* __restrict__ bq, const float* __restrict__ bk, const float* __restrict__ bv,
    const float* __restrict__ x,
    unsigned short* __restrict__ wqkvT, unsigned short* __restrict__ woT,
    unsigned short* __restrict__ w1T, unsigned short* __restrict__ w2T,
    float* __restrict__ bqkv, unsigned short* __restrict__ xb)
{
    __shared__ float tile[32][33];
    const int bid = blockIdx.x;
    const int t = threadIdx.x;
    if (bid < 768) {
        const float* W; unsigned short* Wt; int K, N, xk, yn;
        if (bid < 192) {
            int which = bid >> 6, local = bid & 63;
            W = (which == 0) ? wq : (which == 1 ? wk : wv);
            Wt = wqkvT + which * 65536; K = 256; N = 256;
            xk = local & 7; yn = local >> 3;
        } else if (bid < 256) {
            int local = bid - 192; W = wo; Wt = woT; K = 256; N = 256;
            xk = local & 7; yn = local >> 3;
        } else if (bid < 512) {
            int local = bid - 256; W = w1; Wt = w1T; K = 256; N = 1024;
            xk = local & 7; yn = local >> 3;
        } else {
            int local = bid - 512; W = w2; Wt = w2T; K = 1024; N = 256;
            xk = local & 31; yn = local >> 5;
        }
        const int tx = t & 31, ty = t >> 5;
        const int kb = xk * 32, nb = yn * 32;
#pragma unroll
        for (int i = 0; i < 32; i += 8) tile[ty + i][tx] = W[(size_t)(kb + ty + i) * N + nb + tx];
        __syncthreads();
#pragma unroll
        for (int i = 0; i < 32; i += 8) Wt[(size_t)(nb + ty + i) * K + kb + tx] = bfu(tile[tx][ty + i]);
    } else if (bid < 771) {
        int wb = bid - 768;
        const float* s = (wb == 0) ? bq : (wb == 1 ? bk : bv);
        bqkv[wb * 256 + t] = s[t];
    } else {
        const int i = (bid - 771) * 256 + t;
        float4 v = ((const float4*)x)[i];
        ushort4 o; o.x = bfu(v.x); o.y = bfu(v.y); o.z = bfu(v.z); o.w = bfu(v.w);
        ((ushort4*)xb)[i] = o;
    }
}

// ---------------- QKV GEMM: q/k -> [bh][s][32]; v -> VT [bh][32][2048] pre-swizzled ----------------
__global__ __launch_bounds__(256, 2) void k_qkv(
    const unsigned short* __restrict__ A, const unsigned short* __restrict__ Bt,
    const float* __restrict__ bias,
    unsigned short* __restrict__ qb, unsigned short* __restrict__ kb,
    char* __restrict__ vtg)
{
    __shared__ __align__(16) char As[16384];
    __shared__ __align__(16) char Bs[16384];
    const int t = threadIdx.x;
    const int lane = t & 63, w = t >> 6;
    const int lo = lane & 31, hi = lane >> 5;
    const int row0 = blockIdx.x * 128;
    const int col0 = blockIdx.y * 128;
    f32x16 acc[2][2] = {};
    const int gS = lane & 7;

    for (int kt = 0; kt < 4; ++kt) {
        const int k0 = kt * 64;
#pragma unroll
        for (int i = 0; i < 4; ++i) {
            const int r = w * 32 + i * 8 + (lane >> 3);
            glds16((const char*)(A  + (size_t)(row0 + r) * 256 + k0) + ((gS ^ (r & 7)) << 4),
                   As + w * 4096 + i * 1024 + lane * 16);
            glds16((const char*)(Bt + (size_t)(col0 + r) * 256 + k0) + ((gS ^ (r & 7)) << 4),
                   Bs + w * 4096 + i * 1024 + lane * 16);
        }
        __syncthreads();
        const int rA = (w >> 1) * 64 + lo;
        const int rB = (w & 1) * 64 + lo;
#pragma unroll
        for (int s = 0; s < 4; ++s) {
            const int g = s * 2 + hi;
            bf16x8 fa0 = *(const bf16x8*)(As + rA * 128 + ((g ^ (rA & 7)) << 4));
            bf16x8 fa1 = *(const bf16x8*)(As + (rA + 32) * 128 + ((g ^ (rA & 7)) << 4));
            bf16x8 fb0 = *(const bf16x8*)(Bs + rB * 128 + ((g ^ (rB & 7)) << 4));
            bf16x8 fb1 = *(const bf16x8*)(Bs + (rB + 32) * 128 + ((g ^ (rB & 7)) << 4));
            acc[0][0] = __builtin_amdgcn_mfma_f32_32x32x16_bf16(fa0, fb0, acc[0][0], 0, 0, 0);
            acc[0][1] = __builtin_amdgcn_mfma_f32_32x32x16_bf16(fa0, fb1, acc[0][1], 0, 0, 0);
            acc[1][0] = __builtin_amdgcn_mfma_f32_32x32x16_bf16(fa1, fb0, acc[1][0], 0, 0, 0);
            acc[1][1] = __builtin_amdgcn_mfma_f32_32x32x16_bf16(fa1, fb1, acc[1][1], 0, 0, 0);
        }
        __syncthreads();
    }
#pragma unroll
    for (int m = 0; m < 2; ++m)
#pragma unroll
    for (int n = 0; n < 2; ++n) {
        const int c0 = col0 + (w & 1) * 64 + n * 32;
        const int which = c0 >> 8, h = (c0 >> 5) & 7;
        const float bv = bias[c0 + lo];
        if (which < 2) {
            unsigned short* dst = (which == 0) ? qb : kb;
#pragma unroll
            for (int r = 0; r < 16; ++r) {
                const int gr = row0 + (w >> 1) * 64 + m * 32 + (r & 3) + 8 * (r >> 2) + 4 * hi;
                const int b = gr >> 11, s = gr & 2047;
                dst[(((size_t)(b * 8 + h)) * SQL + s) * 32 + lo] = bfu(acc[m][n][r] + bv);
            }
        } else {
            // V -> VT[bh][d=lo][s], with 8B-unit swizzle within each 128B block:
            // byte o = s*2 -> o' = (o & ~0x78) | ((((o>>3)&15) ^ (lo&15)) << 3)
#pragma unroll
            for (int r = 0; r < 16; ++r) {
                const int gr = row0 + (w >> 1) * 64 + m * 32 + (r & 3) + 8 * (r >> 2) + 4 * hi;
                const int b = gr >> 11, s = gr & 2047;
                const int o = s * 2;
                const int op = (o & ~0x78) | ((((o >> 3) & 15) ^ (lo & 15)) << 3);
                *(unsigned short*)(vtg + ((size_t)(b * 8 + h)) * 131072 + (size_t)lo * 4096 + op)
                    = bfu(acc[m][n][r] + bv);
            }
        }
    }
}

// ---------------- hq/hk from bf16 q/k ----------------
__global__ __launch_bounds__(256) void k_h2(const unsigned short* __restrict__ qb,
                                            const unsigned short* __restrict__ kb,
                                            float* __restrict__ hq, float* __restrict__ hk)
{
    const int gid = blockIdx.x * 256 + threadIdx.x;
    const unsigned short* qp = qb + (size_t)gid * 32;
    const unsigned short* kp = kb + (size_t)gid * 32;
    float sq = 0.f, sk = 0.f;
#pragma unroll
    for (int i = 0; i < 4; ++i) {
        i32x4 qv = *(const i32x4*)(qp + i * 8);
        i32x4 kv = *(const i32x4*)(kp + i * 8);
#pragma unroll
        for (int j = 0; j < 4; ++j) {
            unsigned int qw = (unsigned int)qv[j], kw = (unsigned int)kv[j];
            float a = __builtin_bit_cast(float, qw << 16);
            float c = __builtin_bit_cast(float, qw & 0xffff0000u);
            float d = __builtin_bit_cast(float, kw << 16);
            float e = __builtin_bit_cast(float, kw & 0xffff0000u);
            sq += a * a + c * c; sk += d * d + e * e;
        }
    }
    hq[gid] = NLOG2E_H * sq;
    hk[gid] = NLOG2E_H * sk;
}

// ---------------- MFMA attention: 8 waves, key-split halves, LDS reduce ----------------
__global__ __launch_bounds__(512, 4) void k_attn(
    const unsigned short* __restrict__ qg, const unsigned short* __restrict__ kg,
    const char* __restrict__ vtg, const float* __restrict__ hq,
    const float* __restrict__ hk, unsigned short* __restrict__ ctxb)
{
    __shared__ __align__(16) char kls[8192];     // [2 grp][64 key][32 d] bf16, group-swizzled
    __shared__ __align__(16) char vtl[8192];     // [2 grp][32 d][128 B], pre-swizzled
    __shared__ __align__(16) float hks[128];
    __shared__ __align__(16) float redacc[16 * 256];
    __shared__ __align__(16) float redden[256];
    __shared__ __align__(16) float invs[128];

    const int t = threadIdx.x;
    const int grp = t >> 8;
    const int tl = t & 255;
    const int lane = t & 63;
    const int wv_ = tl >> 6;
    const int lo = lane & 31;
    const int hi = lane >> 5;

    const int bid = blockIdx.x;
    const int qchunk = bid & 15;
    const int bh = bid >> 4;

    const int qrow = qchunk * 128 + wv_ * 32 + lo;
    const unsigned short* qp = qg + ((size_t)bh * SQL + qrow) * 32;
    bf16x8 qf[2];
    qf[0] = *(const bf16x8*)(qp + hi * 8);
    qf[1] = *(const bf16x8*)(qp + 16 + hi * 8);
    const float hqv = hq[(size_t)bh * SQL + qrow];

    f32x16 acc = {};
    float den = 0.f;

    const unsigned short* kbg = kg + (size_t)bh * SQL * 32;
    const char* vtb = vtg + (size_t)bh * 131072;
    char* kd = kls + grp * 4096;
    char* vd = vtl + grp * 4096;

    for (int kt = 0; kt < 16; ++kt) {
        const int key0 = grp * 1024 + kt * 64;
        {
            const int r = tl >> 2, gl = tl & 3;
            glds16((const char*)(kbg + (size_t)(key0 + r) * 32) + ((gl ^ ((r >> 1) & 3)) << 4),
                   kd + tl * 16);
            const int vrw = tl >> 3, vch = tl & 7;
            glds16(vtb + (size_t)vrw * 4096 + key0 * 2 + vch * 16, vd + tl * 16);
            if (tl < 64) hks[grp * 64 + tl] = hk[(size_t)bh * SQL + key0 + tl];
        }
        __syncthreads();

#pragma unroll
        for (int h2 = 0; h2 < 2; ++h2) {
            const int kb32 = h2 * 32;
            const int kA = kb32 + lo;
            const char* krow = kd + kA * 64;
            const int ksw = (kA >> 1) & 3;
            bf16x8 kf0 = *(const bf16x8*)(krow + (((0 + hi) ^ ksw) << 4));
            bf16x8 kf1 = *(const bf16x8*)(krow + (((2 + hi) ^ ksw) << 4));
            f32x16 sc = {};
            sc = __builtin_amdgcn_mfma_f32_32x32x16_bf16(kf0, qf[0], sc, 0, 0, 0);
            sc = __builtin_amdgcn_mfma_f32_32x32x16_bf16(kf1, qf[1], sc, 0, 0, 0);
            const float* hb = &hks[grp * 64 + kb32];
            float4 h0 = *(const float4*)&hb[4 * hi];
            float4 h1 = *(const float4*)&hb[8 + 4 * hi];
            float4 h2v = *(const float4*)&hb[16 + 4 * hi];
            float4 h3 = *(const float4*)&hb[24 + 4 * hi];
            float hkv[16] = {h0.x,h0.y,h0.z,h0.w, h1.x,h1.y,h1.z,h1.w,
                             h2v.x,h2v.y,h2v.z,h2v.w, h3.x,h3.y,h3.z,h3.w};
            float w[16];
#pragma unroll
            for (int r = 0; r < 16; ++r) {
                float arg = fmaf(sc[r], LOG2E, hqv + hkv[r]);
                float e1  = __builtin_amdgcn_exp2f(arg);
                float ww  = __builtin_amdgcn_exp2f(e1 * LOG2E);
                den += ww;
                w[r] = ww;
            }
            i32x4 p0; p0[0]=pk2(w[0],w[1]);  p0[1]=pk2(w[2],w[3]);
                      p0[2]=pk2(w[4],w[5]);  p0[3]=pk2(w[6],w[7]);
            i32x4 p1; p1[0]=pk2(w[8],w[9]);  p1[1]=pk2(w[10],w[11]);
                      p1[2]=pk2(w[12],w[13]); p1[3]=pk2(w[14],w[15]);
            const char* vrow = vd + lo * 128;
            const int vxor = (lo & 15) << 3;
            const int o0 = (kb32 + 4 * hi) * 2;
            const int o1 = (kb32 + 16 + 4 * hi) * 2;
            i32x2 a0 = *(const i32x2*)(vrow + (o0 ^ vxor));
            i32x2 a1 = *(const i32x2*)(vrow + ((o0 + 16) ^ vxor));
            i32x2 b0 = *(const i32x2*)(vrow + (o1 ^ vxor));
            i32x2 b1 = *(const i32x2*)(vrow + ((o1 + 16) ^ vxor));
            i32x4 vb0; vb0[0]=a0[0]; vb0[1]=a0[1]; vb0[2]=a1[0]; vb0[3]=a1[1];
            i32x4 vb1; vb1[0]=b0[0]; vb1[1]=b0[1]; vb1[2]=b1[0]; vb1[3]=b1[1];
            acc = __builtin_amdgcn_mfma_f32_32x32x16_bf16(
                __builtin_bit_cast(bf16x8, p0), __builtin_bit_cast(bf16x8, vb0), acc, 0, 0, 0);
            acc = __builtin_amdgcn_mfma_f32_32x32x16_bf16(
                __builtin_bit_cast(bf16x8, p1), __builtin_bit_cast(bf16x8, vb1), acc, 0, 0, 0);
        }
        __syncthreads();
    }

    // ---- cross-group reduction ----
    if (grp == 1) {
#pragma unroll
        for (int r = 0; r < 16; ++r) redacc[r * 256 + tl] = acc[r];
        redden[tl] = den;
    }
    __syncthreads();
    if (grp == 0) {
#pragma unroll
        for (int r = 0; r < 16; ++r) acc[r] += redacc[r * 256 + tl];
        den += redden[tl];
    }
    const float dfull = den + __shfl_xor(den, 32);
    if (grp == 0 && hi == 0) invs[wv_ * 32 + lo] = 1.f / dfull;
    __syncthreads();
    if (grp == 0) {
        float4 i0 = *(const float4*)&invs[wv_ * 32 + 4 * hi];
        float4 i1 = *(const float4*)&invs[wv_ * 32 + 8 + 4 * hi];
        float4 i2 = *(const float4*)&invs[wv_ * 32 + 16 + 4 * hi];
        float4 i3 = *(const float4*)&invs[wv_ * 32 + 24 + 4 * hi];
        float iv[16] = {i0.x,i0.y,i0.z,i0.w, i1.x,i1.y,i1.z,i1.w,
                        i2.x,i2.y,i2.z,i2.w, i3.x,i3.y,i3.z,i3.w};
        const int b = bh >> 3, h = bh & 7;
        unsigned short* cbase = ctxb + ((size_t)(b * SQL + qchunk * 128 + wv_ * 32)) * 256 + h * 32 + lo;
#pragma unroll
        for (int r = 0; r < 16; ++r) {
            const int qr = (r & 3) + 8 * (r >> 2) + 4 * hi;
            cbase[(size_t)qr * 256] = bfu(acc[r] * iv[r]);
        }
    }
}

// ---------------- generic MFMA GEMM with split-K via blockIdx.z ----------------
template<int KSTRIDE, int KHALF, int NFULL, int RELU, int OUTF, int OUTB>
__global__ __launch_bounds__(256, 2) void k_gemm(
    const unsigned short* __restrict__ A, const unsigned short* __restrict__ Bt,
    const float* __restrict__ bias,
    float* __restrict__ outf, unsigned short* __restrict__ outb)
{
    __shared__ __align__(16) char As[16384];
    __shared__ __align__(16) char Bs[16384];
    const int t = threadIdx.x;
    const int lane = t & 63, w = t >> 6;
    const int lo = lane & 31, hi = lane >> 5;
    const int row0 = blockIdx.x * 128;
    const int col0 = blockIdx.y * 128;
    const int z = blockIdx.z;
    f32x16 acc[2][2] = {};
    const int gS = lane & 7;

    for (int kt = 0; kt < KHALF; ++kt) {
        const int k0 = (z * KHALF + kt) * 64;
#pragma unroll
        for (int i = 0; i < 4; ++i) {
            const int r = w * 32 + i * 8 + (lane >> 3);
            glds16((const char*)(A  + (size_t)(row0 + r) * KSTRIDE + k0) + ((gS ^ (r & 7)) << 4),
                   As + w * 4096 + i * 1024 + lane * 16);
            glds16((const char*)(Bt + (size_t)(col0 + r) * KSTRIDE + k0) + ((gS ^ (r & 7)) << 4),
                   Bs + w * 4096 + i * 1024 + lane * 16);
        }
        __syncthreads();
        const int rA = (w >> 1) * 64 + lo;
        const int rB = (w & 1) * 64 + lo;
#pragma unroll
        for (int s = 0; s < 4; ++s) {
            const int g = s * 2 + hi;
            bf16x8 fa0 = *(const bf16x8*)(As + rA * 128 + ((g ^ (rA & 7)) << 4));
            bf16x8 fa1 = *(const bf16x8*)(As + (rA + 32) * 128 + ((g ^ (rA & 7)) << 4));
            bf16x8 fb0 = *(const bf16x8*)(Bs + rB * 128 + ((g ^ (rB & 7)) << 4));
            bf16x8 fb1 = *(const bf16x8*)(Bs + (rB + 32) * 128 + ((g ^ (rB & 7)) << 4));
            acc[0][0] = __builtin_amdgcn_mfma_f32_32x32x16_bf16(fa0, fb0, acc[0][0], 0, 0, 0);
            acc[0][1] = __builtin_amdgcn_mfma_f32_32x32x16_bf16(fa0, fb1, acc[0][1], 0, 0, 0);
            acc[1][0] = __builtin_amdgcn_mfma_f32_32x32x16_bf16(fa1, fb0, acc[1][0], 0, 0, 0);
            acc[1][1] = __builtin_amdgcn_mfma_f32_32x32x16_bf16(fa1, fb1, acc[1][1], 0, 0, 0);
        }
        __syncthreads();
    }
#pragma unroll
    for (int m = 0; m < 2; ++m)
#pragma unroll
    for (int n = 0; n < 2; ++n) {
        const int c0 = col0 + (w & 1) * 64 + n * 32;
        const float bv = (z == 0) ? bias[c0 + lo] : 0.f;
#pragma unroll
        for (int r = 0; r < 16; ++r) {
            const int gr = row0 + (w >> 1) * 64 + m * 32 + (r & 3) + 8 * (r >> 2) + 4 * hi;
            float vv = acc[m][n][r] + bv;
            if (RELU) vv = fmaxf(vv, 0.f);
            if (OUTF) outf[(size_t)z * 8192 * NFULL + (size_t)gr * NFULL + c0 + lo] = vv;
            if (OUTB) outb[(size_t)gr * NFULL + c0 + lo] = bfu(vv);
        }
    }
}

// ---------------- fused partial-sum + residual + LayerNorm ----------------
template<int DUAL>
__global__ __launch_bounds__(256) void k_lnsum(
    const float* __restrict__ pa, const float* __restrict__ pb,
    const float* __restrict__ res, const float* __restrict__ g,
    const float* __restrict__ bt, float* __restrict__ outf,
    unsigned short* __restrict__ outb)
{
    const int row = blockIdx.x * 4 + (threadIdx.x >> 6);
    const int lane = threadIdx.x & 63;
    const size_t base = (size_t)row * 256;
    float4 v  = ((const float4*)(pa + base))[lane];
    float4 v2 = ((const float4*)(pb + base))[lane];
    float4 v3 = ((const float4*)(res + base))[lane];
    v.x += v2.x + v3.x; v.y += v2.y + v3.y; v.z += v2.z + v3.z; v.w += v2.w + v3.w;
    float s  = v.x + v.y + v.z + v.w;
    float ss = v.x * v.x + v.y * v.y + v.z * v.z + v.w * v.w;
#pragma unroll
    for (int off = 32; off; off >>= 1) { s += __shfl_xor(s, off); ss += __shfl_xor(ss, off); }
    const float mu = s * (1.f / 256.f);
    const float rstd = rsqrtf(ss * (1.f / 256.f) - mu * mu + LNEPS);
    const float4 gg = ((const float4*)g)[lane];
    const float4 bb = ((const float4*)bt)[lane];
    float4 o;
    o.x = (v.x - mu) * rstd * gg.x + bb.x;
    o.y = (v.y - mu) * rstd * gg.y + bb.y;
    o.z = (v.z - mu) * rstd * gg.z + bb.z;
    o.w = (v.w - mu) * rstd * gg.w + bb.w;
    ((float4*)(outf + base))[lane] = o;
    if (DUAL) {
        ushort4 ob; ob.x = bfu(o.x); ob.y = bfu(o.y); ob.z = bfu(o.z); ob.w = bfu(o.w);
        ((ushort4*)(outb + base))[lane] = ob;
    }
}

extern "C" void kernel_launch(void* const* d_in, const int* in_sizes, int n_in,
                              void* d_out, int out_size, void* d_ws, size_t ws_size,
                              hipStream_t stream) {
    const float* x   = (const float*)d_in[0];
    const float* wq  = (const float*)d_in[1];  const float* bq  = (const float*)d_in[2];
    const float* wk  = (const float*)d_in[3];  const float* bk  = (const float*)d_in[4];
    const float* wv  = (const float*)d_in[5];  const float* bv  = (const float*)d_in[6];
    const float* wo  = (const float*)d_in[7];  const float* wob = (const float*)d_in[8];
    const float* w1  = (const float*)d_in[9];  const float* b1  = (const float*)d_in[10];
    const float* w2  = (const float*)d_in[11]; const float* b2  = (const float*)d_in[12];
    const float* g1  = (const float*)d_in[13]; const float* bl1 = (const float*)d_in[14];
    const float* g2  = (const float*)d_in[15]; const float* bl2 = (const float*)d_in[16];

    char* ws = (char*)d_ws;
    unsigned short* xb    = (unsigned short*)(ws + B_XB);
    unsigned short* qb    = (unsigned short*)(ws + B_QB);
    unsigned short* kbuf  = (unsigned short*)(ws + B_KB);
    char*           vt    = (char*)(ws + B_VT);
    unsigned short* ctxb  = (unsigned short*)(ws + B_CTX);
    unsigned short* o1b   = (unsigned short*)(ws + B_O1B);
    float*          o1f   = (float*)(ws + B_O1F);
    unsigned short* mid   = (unsigned short*)(ws + B_MID);
    float*          c1    = (float*)(ws + B_MID);    // partials, dead before mid written
    float*          c2    = (float*)(ws + B_C2);     // partials, alias xb/qb/kb/vt (dead)
    unsigned short* wqkvT = (unsigned short*)(ws + B_WQKVT);
    unsigned short* woT   = (unsigned short*)(ws + B_WOT);
    unsigned short* w1T   = (unsigned short*)(ws + B_W1T);
    unsigned short* w2T   = (unsigned short*)(ws + B_W2T);
    float* bqkv = (float*)(ws + B_BQKV);
    float* hqb  = (float*)(ws + B_HQ);
    float* hkb  = (float*)(ws + B_HK);
    float* out  = (float*)d_out;

    k_packall<<<dim3(2819), dim3(256), 0, stream>>>(wq, wk, wv, wo, w1, w2, bq, bk, bv, x,
                                                    wqkvT, woT, w1T, w2T, bqkv, xb);
    k_qkv<<<dim3(64, 6), dim3(256), 0, stream>>>(xb, wqkvT, bqkv, qb, kbuf, vt);
    k_h2<<<dim3(256), dim3(256), 0, stream>>>(qb, kbuf, hqb, hkb);
    k_attn<<<dim3(512), dim3(512), 0, stream>>>(qb, kbuf, vt, hqb, hkb, ctxb);
    k_gemm<256, 2, 256, 0, 1, 0><<<dim3(64, 2, 2), dim3(256), 0, stream>>>(ctxb, woT, wob, c1, nullptr);
    k_lnsum<1><<<dim3(2048), dim3(256), 0, stream>>>(c1, c1 + 2097152, x, g1, bl1, o1f, o1b);
    k_gemm<256, 4, 1024, 1, 0, 1><<<dim3(64, 8, 1), dim3(256), 0, stream>>>(o1b, w1T, b1, nullptr, mid);
    k_gemm<1024, 8, 256, 0, 1, 0><<<dim3(64, 2, 2), dim3(256), 0, stream>>>(mid, w2T, b2, c2, nullptr);
    k_lnsum<0><<<dim3(2048), dim3(256), 0, stream>>>(c2, c2 + 2097152, o1f, g2, bl2, out, nullptr);
}

// Round 5
// 195.286 us; speedup vs baseline: 4.1890x; 1.0199x over previous
//
#include <hip/hip_runtime.h>
#include <hip/hip_bf16.h>

#define SQL  2048
#define DM   256
#define LNEPS 1e-6f
#define LOG2E    (1.44269504f)

// ---- workspace layout (byte offsets) ----
#define B_XB    (0ull)            // 4 MB  x bf16 [8192][256]
#define B_QB    (4ull<<20)        // 4 MB  q bf16 [bh][s][32]  (pre-scaled by log2e)
#define B_KB    (8ull<<20)        // 4 MB  k bf16 [bh][s][32]
#define B_VT    (12ull<<20)       // 4 MB  V^T bf16 [bh][32][2048], pre-swizzled
#define B_CTX   (16ull<<20)       // 4 MB  ctx bf16 [8192][256]
#define B_O1B   (20ull<<20)       // 4 MB  out1 bf16
#define B_O1F   (24ull<<20)       // 8 MB  out1 f32
#define B_MID   (32ull<<20)       // 16 MB mid bf16 [8192][1024]; ALSO c1 partials (2x8MB)
#define B_WQKVT (48ull<<20)       // 384 KB bf16 [768][256]
#define B_WOT   ((48ull<<20)+(512ull<<10))  // 128 KB
#define B_W1T   (49ull<<20)       // 512 KB bf16 [1024][256]
#define B_W2T   ((49ull<<20)+(512ull<<10))  // 512 KB bf16 [256][1024]
#define B_BQKV  (50ull<<20)       // 3 KB f32
#define B_HQ    ((50ull<<20)+(64ull<<10))   // 256 KB f32
#define B_HK    ((50ull<<20)+(320ull<<10))  // 256 KB f32
#define B_C2    (0ull)            // 16 MB f32 partials (alias xb/qb/kb/vt, dead)

typedef float  f32x16 __attribute__((ext_vector_type(16)));
typedef short  bf16x8 __attribute__((ext_vector_type(8)));
typedef int    i32x4  __attribute__((ext_vector_type(4)));
typedef int    i32x2  __attribute__((ext_vector_type(2)));

static __device__ __forceinline__ unsigned short bfu(float f){
    __hip_bfloat16 h = __float2bfloat16(f);
    return *reinterpret_cast<unsigned short*>(&h);
}
static __device__ __forceinline__ unsigned pk2(float a, float b){
    return (unsigned)bfu(a) | ((unsigned)bfu(b) << 16);
}
static __device__ __forceinline__ void glds16(const void* g, void* l){
    __builtin_amdgcn_global_load_lds((const __attribute__((address_space(1))) unsigned int*)g,
                                     (__attribute__((address_space(3))) unsigned int*)l, 16, 0, 0);
}

// ---------------- fused packing: weights->bf16^T, biases, x->bf16 ----------------
__global__ __launch_bounds__(256) void k_packall(
    const float* __restrict__ wq, const float* __restrict__ wk, const float* __restrict__ wv,
    const float* __restrict__ wo, const float* __restrict__ w1, const float* __restrict__ w2,
    const float* __restrict__ bq, const float* __restrict__ bk, const float* __restrict__ bv,
    const float* __restrict__ x,
    unsigned short* __restrict__ wqkvT, unsigned short* __restrict__ woT,
    unsigned short* __restrict__ w1T, unsigned short* __restrict__ w2T,
    float* __restrict__ bqkv, unsigned short* __restrict__ xb)
{
    __shared__ float tile[32][33];
    const int bid = blockIdx.x;
    const int t = threadIdx.x;
    if (bid < 768) {
        const float* W; unsigned short* Wt; int K, N, xk, yn;
        if (bid < 192) {
            int which = bid >> 6, local = bid & 63;
            W = (which == 0) ? wq : (which == 1 ? wk : wv);
            Wt = wqkvT + which * 65536; K = 256; N = 256;
            xk = local & 7; yn = local >> 3;
        } else if (bid < 256) {
            int local = bid - 192; W = wo; Wt = woT; K = 256; N = 256;
            xk = local & 7; yn = local >> 3;
        } else if (bid < 512) {
            int local = bid - 256; W = w1; Wt = w1T; K = 256; N = 1024;
            xk = local & 7; yn = local >> 3;
        } else {
            int local = bid - 512; W = w2; Wt = w2T; K = 1024; N = 256;
            xk = local & 31; yn = local >> 5;
        }
        const int tx = t & 31, ty = t >> 5;
        const int kb = xk * 32, nb = yn * 32;
#pragma unroll
        for (int i = 0; i < 32; i += 8) tile[ty + i][tx] = W[(size_t)(kb + ty + i) * N + nb + tx];
        __syncthreads();
#pragma unroll
        for (int i = 0; i < 32; i += 8) Wt[(size_t)(nb + ty + i) * K + kb + tx] = bfu(tile[tx][ty + i]);
    } else if (bid < 771) {
        int wb = bid - 768;
        const float* s = (wb == 0) ? bq : (wb == 1 ? bk : bv);
        bqkv[wb * 256 + t] = s[t];
    } else {
        const int i = (bid - 771) * 256 + t;
        float4 v = ((const float4*)x)[i];
        ushort4 o; o.x = bfu(v.x); o.y = bfu(v.y); o.z = bfu(v.z); o.w = bfu(v.w);
        ((ushort4*)xb)[i] = o;
    }
}

// ---------------- QKV GEMM (2-phase dbuf): q scaled by log2e; v -> VT pre-swizzled ----------------
__global__ __launch_bounds__(256, 2) void k_qkv(
    const unsigned short* __restrict__ A, const unsigned short* __restrict__ Bt,
    const float* __restrict__ bias,
    unsigned short* __restrict__ qb, unsigned short* __restrict__ kb,
    char* __restrict__ vtg)
{
    __shared__ __align__(16) char smem[65536];
    const int t = threadIdx.x;
    const int lane = t & 63, w = t >> 6;
    const int lo = lane & 31, hi = lane >> 5;
    const int row0 = blockIdx.x * 128;
    const int col0 = blockIdx.y * 128;
    f32x16 acc[2][2] = {};
    const int gS = lane & 7;
    const int rr = w * 32 + (lane >> 3);

    auto stage = [&](int buf, int kt) {
        const int k0 = kt * 64;
        char* As = smem + buf * 32768;
        char* Bs = As + 16384;
#pragma unroll
        for (int i = 0; i < 4; ++i) {
            const int r = rr + i * 8;
            glds16((const char*)(A  + (size_t)(row0 + r) * 256 + k0) + ((gS ^ (r & 7)) << 4),
                   As + w * 4096 + i * 1024 + lane * 16);
            glds16((const char*)(Bt + (size_t)(col0 + r) * 256 + k0) + ((gS ^ (r & 7)) << 4),
                   Bs + w * 4096 + i * 1024 + lane * 16);
        }
    };

    stage(0, 0);
    __syncthreads();
    for (int kt = 0; kt < 4; ++kt) {
        if (kt + 1 < 4) stage((kt + 1) & 1, kt + 1);
        const char* As = smem + (kt & 1) * 32768;
        const char* Bs = As + 16384;
        const int rA = (w >> 1) * 64 + lo;
        const int rB = (w & 1) * 64 + lo;
#pragma unroll
        for (int s = 0; s < 4; ++s) {
            const int g = s * 2 + hi;
            bf16x8 fa0 = *(const bf16x8*)(As + rA * 128 + ((g ^ (rA & 7)) << 4));
            bf16x8 fa1 = *(const bf16x8*)(As + (rA + 32) * 128 + ((g ^ (rA & 7)) << 4));
            bf16x8 fb0 = *(const bf16x8*)(Bs + rB * 128 + ((g ^ (rB & 7)) << 4));
            bf16x8 fb1 = *(const bf16x8*)(Bs + (rB + 32) * 128 + ((g ^ (rB & 7)) << 4));
            acc[0][0] = __builtin_amdgcn_mfma_f32_32x32x16_bf16(fa0, fb0, acc[0][0], 0, 0, 0);
            acc[0][1] = __builtin_amdgcn_mfma_f32_32x32x16_bf16(fa0, fb1, acc[0][1], 0, 0, 0);
            acc[1][0] = __builtin_amdgcn_mfma_f32_32x32x16_bf16(fa1, fb0, acc[1][0], 0, 0, 0);
            acc[1][1] = __builtin_amdgcn_mfma_f32_32x32x16_bf16(fa1, fb1, acc[1][1], 0, 0, 0);
        }
        __syncthreads();
    }
#pragma unroll
    for (int m = 0; m < 2; ++m)
#pragma unroll
    for (int n = 0; n < 2; ++n) {
        const int c0 = col0 + (w & 1) * 64 + n * 32;
        const int which = c0 >> 8, h = (c0 >> 5) & 7;
        const float bv = bias[c0 + lo];
        if (which < 2) {
            unsigned short* dst = (which == 0) ? qb : kb;
            const float scl = (which == 0) ? LOG2E : 1.0f;
#pragma unroll
            for (int r = 0; r < 16; ++r) {
                const int gr = row0 + (w >> 1) * 64 + m * 32 + (r & 3) + 8 * (r >> 2) + 4 * hi;
                const int b = gr >> 11, s = gr & 2047;
                dst[(((size_t)(b * 8 + h)) * SQL + s) * 32 + lo] = bfu((acc[m][n][r] + bv) * scl);
            }
        } else {
#pragma unroll
            for (int r = 0; r < 16; ++r) {
                const int gr = row0 + (w >> 1) * 64 + m * 32 + (r & 3) + 8 * (r >> 2) + 4 * hi;
                const int b = gr >> 11, s = gr & 2047;
                const int o = s * 2;
                const int op = (o & ~0x78) | ((((o >> 3) & 15) ^ (lo & 15)) << 3);
                *(unsigned short*)(vtg + ((size_t)(b * 8 + h)) * 131072 + (size_t)lo * 4096 + op)
                    = bfu(acc[m][n][r] + bv);
            }
        }
    }
}

// ---------------- hq/hk (q stored pre-scaled by log2e) ----------------
__global__ __launch_bounds__(256) void k_h2(const unsigned short* __restrict__ qb,
                                            const unsigned short* __restrict__ kb,
                                            float* __restrict__ hq, float* __restrict__ hk)
{
    const int gid = blockIdx.x * 256 + threadIdx.x;
    const unsigned short* qp = qb + (size_t)gid * 32;
    const unsigned short* kp = kb + (size_t)gid * 32;
    float sq = 0.f, sk = 0.f;
#pragma unroll
    for (int i = 0; i < 4; ++i) {
        i32x4 qv = *(const i32x4*)(qp + i * 8);
        i32x4 kv = *(const i32x4*)(kp + i * 8);
#pragma unroll
        for (int j = 0; j < 4; ++j) {
            unsigned int qw = (unsigned int)qv[j], kw = (unsigned int)kv[j];
            float a = __builtin_bit_cast(float, qw << 16);
            float c = __builtin_bit_cast(float, qw & 0xffff0000u);
            float d = __builtin_bit_cast(float, kw << 16);
            float e = __builtin_bit_cast(float, kw & 0xffff0000u);
            sq += a * a + c * c; sk += d * d + e * e;
        }
    }
    // hq' = -0.5*log2e*||q||^2 + log2(log2e)   (q was pre-scaled by log2e)
    hq[gid] = -0.34657359f * sq + 0.52876637f;
    hk[gid] = -0.72134752f * sk;
}

// ---------------- MFMA attention: 4 key-groups x 2 q-waves, hq/hk folded into MFMA ----------------
__global__ __launch_bounds__(512, 4) void k_attn(
    const unsigned short* __restrict__ qg, const unsigned short* __restrict__ kg,
    const char* __restrict__ vtg, const float* __restrict__ hq,
    const float* __restrict__ hk, unsigned short* __restrict__ ctxb)
{
    __shared__ __align__(16) char kls[16384];    // [4 grp][64 key][32 d] bf16, chunk-swizzled
    __shared__ __align__(16) char vtl[16384];    // [4 grp][32 d][128 B], pre-swizzled
    __shared__ __align__(16) float hks[256];
    __shared__ __align__(16) float redacc[3 * 16 * 128];
    __shared__ __align__(16) float redden[3 * 128];
    __shared__ __align__(16) float invs[64];

    const int t = threadIdx.x;
    const int grp = t >> 7;          // 0..3 key-group
    const int tl  = t & 127;
    const int lane = t & 63;
    const int w   = (t >> 6) & 1;    // wave-in-group (q sub-block)
    const int lo = lane & 31;
    const int hi = lane >> 5;

    const int bid = blockIdx.x;
    const int qc = bid & 31;
    const int bh = bid >> 5;

    const int qrow = qc * 64 + w * 32 + lo;
    const unsigned short* qp = qg + ((size_t)bh * SQL + qrow) * 32;
    bf16x8 qf0 = *(const bf16x8*)(qp + hi * 8);
    bf16x8 qf1 = *(const bf16x8*)(qp + 16 + hi * 8);
    const float hqv = hq[(size_t)bh * SQL + qrow];

    // loop-invariant B3 frag: k-slots {0:1.0, 1:hq'} on hi==0 lanes
    i32x4 b3i = {};
    if (hi == 0) b3i[0] = 0x3F80u | ((unsigned)bfu(hqv) << 16);
    const bf16x8 b3 = __builtin_bit_cast(bf16x8, b3i);

    f32x16 acc = {};
    float den = 0.f;

    const unsigned short* kbg = kg + (size_t)bh * SQL * 32;
    const char* vtb = vtg + (size_t)bh * 131072;
    char* kd = kls + grp * 4096;
    char* vd = vtl + grp * 4096;

    for (int kt = 0; kt < 8; ++kt) {
        const int key0 = grp * 512 + kt * 64;
        {
#pragma unroll
            for (int it = 0; it < 2; ++it) {
                const int idx = it * 128 + tl;
                const int r = idx >> 2, gl = idx & 3;
                glds16((const char*)(kbg + (size_t)(key0 + r) * 32) + ((gl ^ ((r >> 1) & 3)) << 4),
                       kd + idx * 16);
                const int vrw = idx >> 3, vch = idx & 7;
                glds16(vtb + (size_t)vrw * 4096 + key0 * 2 + vch * 16, vd + idx * 16);
            }
            if (tl < 64) hks[grp * 64 + tl] = hk[(size_t)bh * SQL + key0 + tl];
        }
        __syncthreads();

#pragma unroll
        for (int h2 = 0; h2 < 2; ++h2) {
            const int kb32 = h2 * 32;
            const int kA = kb32 + lo;
            const char* krow = kd + kA * 64;
            const int ksw = (kA >> 1) & 3;
            bf16x8 kf0 = *(const bf16x8*)(krow + (((0 + hi) ^ ksw) << 4));
            bf16x8 kf1 = *(const bf16x8*)(krow + (((2 + hi) ^ ksw) << 4));
            // A3 frag: k-slots {0: hk[key], 1: 1.0} on hi==0 lanes
            i32x4 a3i = {};
            if (hi == 0) a3i[0] = (unsigned)bfu(hks[grp * 64 + kA]) | 0x3F800000u;
            f32x16 sc = {};
            sc = __builtin_amdgcn_mfma_f32_32x32x16_bf16(kf0, qf0, sc, 0, 0, 0);
            sc = __builtin_amdgcn_mfma_f32_32x32x16_bf16(kf1, qf1, sc, 0, 0, 0);
            sc = __builtin_amdgcn_mfma_f32_32x32x16_bf16(
                     __builtin_bit_cast(bf16x8, a3i), b3, sc, 0, 0, 0);
            float wv[16];
#pragma unroll
            for (int r = 0; r < 16; ++r) {
                float e1 = __builtin_amdgcn_exp2f(sc[r]);   // = log2e * exp(-0.5 d)
                float ww = __builtin_amdgcn_exp2f(e1);      // = e^{exp(-0.5 d)}
                den += ww;
                wv[r] = ww;
            }
            i32x4 p0; p0[0]=pk2(wv[0],wv[1]);   p0[1]=pk2(wv[2],wv[3]);
                      p0[2]=pk2(wv[4],wv[5]);   p0[3]=pk2(wv[6],wv[7]);
            i32x4 p1; p1[0]=pk2(wv[8],wv[9]);   p1[1]=pk2(wv[10],wv[11]);
                      p1[2]=pk2(wv[12],wv[13]); p1[3]=pk2(wv[14],wv[15]);
            const char* vrow = vd + lo * 128;
            const int vxor = (lo & 15) << 3;
            const int o0 = (kb32 + 4 * hi) * 2;
            const int o1 = (kb32 + 16 + 4 * hi) * 2;
            i32x2 a0 = *(const i32x2*)(vrow + (o0 ^ vxor));
            i32x2 a1 = *(const i32x2*)(vrow + ((o0 + 16) ^ vxor));
            i32x2 b0 = *(const i32x2*)(vrow + (o1 ^ vxor));
            i32x2 b1 = *(const i32x2*)(vrow + ((o1 + 16) ^ vxor));
            i32x4 vb0; vb0[0]=a0[0]; vb0[1]=a0[1]; vb0[2]=a1[0]; vb0[3]=a1[1];
            i32x4 vb1; vb1[0]=b0[0]; vb1[1]=b0[1]; vb1[2]=b1[0]; vb1[3]=b1[1];
            acc = __builtin_amdgcn_mfma_f32_32x32x16_bf16(
                __builtin_bit_cast(bf16x8, p0), __builtin_bit_cast(bf16x8, vb0), acc, 0, 0, 0);
            acc = __builtin_amdgcn_mfma_f32_32x32x16_bf16(
                __builtin_bit_cast(bf16x8, p1), __builtin_bit_cast(bf16x8, vb1), acc, 0, 0, 0);
        }
        __syncthreads();
    }

    // ---- cross-group tree reduction ----
    if (grp != 0) {
#pragma unroll
        for (int r = 0; r < 16; ++r) redacc[((grp - 1) * 16 + r) * 128 + tl] = acc[r];
        redden[(grp - 1) * 128 + tl] = den;
    }
    __syncthreads();
    if (grp == 0) {
#pragma unroll
        for (int r = 0; r < 16; ++r)
            acc[r] += redacc[r * 128 + tl] + redacc[(16 + r) * 128 + tl] + redacc[(32 + r) * 128 + tl];
        den += redden[tl] + redden[128 + tl] + redden[256 + tl];
        const float dfull = den + __shfl_xor(den, 32);
        if (hi == 0) invs[w * 32 + lo] = 1.f / dfull;
        // same-wave LDS write->read, no barrier needed
        float4 i0 = *(const float4*)&invs[w * 32 + 4 * hi];
        float4 i1 = *(const float4*)&invs[w * 32 + 8 + 4 * hi];
        float4 i2 = *(const float4*)&invs[w * 32 + 16 + 4 * hi];
        float4 i3 = *(const float4*)&invs[w * 32 + 24 + 4 * hi];
        float iv[16] = {i0.x,i0.y,i0.z,i0.w, i1.x,i1.y,i1.z,i1.w,
                        i2.x,i2.y,i2.z,i2.w, i3.x,i3.y,i3.z,i3.w};
        const int b = bh >> 3, h = bh & 7;
        unsigned short* cbase = ctxb + ((size_t)(b * SQL + qc * 64 + w * 32)) * 256 + h * 32 + lo;
#pragma unroll
        for (int r = 0; r < 16; ++r) {
            const int qr = (r & 3) + 8 * (r >> 2) + 4 * hi;
            cbase[(size_t)qr * 256] = bfu(acc[r] * iv[r]);
        }
    }
}

// ---------------- generic MFMA GEMM, 2-phase dbuf, split-K via blockIdx.z ----------------
template<int KSTRIDE, int KT, int NFULL, int RELU, int OUTF, int OUTB>
__global__ __launch_bounds__(256, 2) void k_gemm(
    const unsigned short* __restrict__ A, const unsigned short* __restrict__ Bt,
    const float* __restrict__ bias,
    float* __restrict__ outf, unsigned short* __restrict__ outb)
{
    __shared__ __align__(16) char smem[65536];
    const int t = threadIdx.x;
    const int lane = t & 63, w = t >> 6;
    const int lo = lane & 31, hi = lane >> 5;
    const int row0 = blockIdx.x * 128;
    const int col0 = blockIdx.y * 128;
    const int z = blockIdx.z;
    f32x16 acc[2][2] = {};
    const int gS = lane & 7;
    const int rr = w * 32 + (lane >> 3);

    auto stage = [&](int buf, int kt) {
        const int k0 = (z * KT + kt) * 64;
        char* As = smem + buf * 32768;
        char* Bs = As + 16384;
#pragma unroll
        for (int i = 0; i < 4; ++i) {
            const int r = rr + i * 8;
            glds16((const char*)(A  + (size_t)(row0 + r) * KSTRIDE + k0) + ((gS ^ (r & 7)) << 4),
                   As + w * 4096 + i * 1024 + lane * 16);
            glds16((const char*)(Bt + (size_t)(col0 + r) * KSTRIDE + k0) + ((gS ^ (r & 7)) << 4),
                   Bs + w * 4096 + i * 1024 + lane * 16);
        }
    };

    stage(0, 0);
    __syncthreads();
    for (int kt = 0; kt < KT; ++kt) {
        if (kt + 1 < KT) stage((kt + 1) & 1, kt + 1);
        const char* As = smem + (kt & 1) * 32768;
        const char* Bs = As + 16384;
        const int rA = (w >> 1) * 64 + lo;
        const int rB = (w & 1) * 64 + lo;
#pragma unroll
        for (int s = 0; s < 4; ++s) {
            const int g = s * 2 + hi;
            bf16x8 fa0 = *(const bf16x8*)(As + rA * 128 + ((g ^ (rA & 7)) << 4));
            bf16x8 fa1 = *(const bf16x8*)(As + (rA + 32) * 128 + ((g ^ (rA & 7)) << 4));
            bf16x8 fb0 = *(const bf16x8*)(Bs + rB * 128 + ((g ^ (rB & 7)) << 4));
            bf16x8 fb1 = *(const bf16x8*)(Bs + (rB + 32) * 128 + ((g ^ (rB & 7)) << 4));
            acc[0][0] = __builtin_amdgcn_mfma_f32_32x32x16_bf16(fa0, fb0, acc[0][0], 0, 0, 0);
            acc[0][1] = __builtin_amdgcn_mfma_f32_32x32x16_bf16(fa0, fb1, acc[0][1], 0, 0, 0);
            acc[1][0] = __builtin_amdgcn_mfma_f32_32x32x16_bf16(fa1, fb0, acc[1][0], 0, 0, 0);
            acc[1][1] = __builtin_amdgcn_mfma_f32_32x32x16_bf16(fa1, fb1, acc[1][1], 0, 0, 0);
        }
        __syncthreads();
    }
#pragma unroll
    for (int m = 0; m < 2; ++m)
#pragma unroll
    for (int n = 0; n < 2; ++n) {
        const int c0 = col0 + (w & 1) * 64 + n * 32;
        const float bv = (z == 0) ? bias[c0 + lo] : 0.f;
#pragma unroll
        for (int r = 0; r < 16; ++r) {
            const int gr = row0 + (w >> 1) * 64 + m * 32 + (r & 3) + 8 * (r >> 2) + 4 * hi;
            float vv = acc[m][n][r] + bv;
            if (RELU) vv = fmaxf(vv, 0.f);
            if (OUTF) outf[(size_t)z * 8192 * NFULL + (size_t)gr * NFULL + c0 + lo] = vv;
            if (OUTB) outb[(size_t)gr * NFULL + c0 + lo] = bfu(vv);
        }
    }
}

// ---------------- fused partial-sum + residual + LayerNorm ----------------
template<int DUAL>
__global__ __launch_bounds__(256) void k_lnsum(
    const float* __restrict__ pa, const float* __restrict__ pb,
    const float* __restrict__ res, const float* __restrict__ g,
    const float* __restrict__ bt, float* __restrict__ outf,
    unsigned short* __restrict__ outb)
{
    const int row = blockIdx.x * 4 + (threadIdx.x >> 6);
    const int lane = threadIdx.x & 63;
    const size_t base = (size_t)row * 256;
    float4 v  = ((const float4*)(pa + base))[lane];
    float4 v2 = ((const float4*)(pb + base))[lane];
    float4 v3 = ((const float4*)(res + base))[lane];
    v.x += v2.x + v3.x; v.y += v2.y + v3.y; v.z += v2.z + v3.z; v.w += v2.w + v3.w;
    float s  = v.x + v.y + v.z + v.w;
    float ss = v.x * v.x + v.y * v.y + v.z * v.z + v.w * v.w;
#pragma unroll
    for (int off = 32; off; off >>= 1) { s += __shfl_xor(s, off); ss += __shfl_xor(ss, off); }
    const float mu = s * (1.f / 256.f);
    const float rstd = rsqrtf(ss * (1.f / 256.f) - mu * mu + LNEPS);
    const float4 gg = ((const float4*)g)[lane];
    const float4 bb = ((const float4*)bt)[lane];
    float4 o;
    o.x = (v.x - mu) * rstd * gg.x + bb.x;
    o.y = (v.y - mu) * rstd * gg.y + bb.y;
    o.z = (v.z - mu) * rstd * gg.z + bb.z;
    o.w = (v.w - mu) * rstd * gg.w + bb.w;
    ((float4*)(outf + base))[lane] = o;
    if (DUAL) {
        ushort4 ob; ob.x = bfu(o.x); ob.y = bfu(o.y); ob.z = bfu(o.z); ob.w = bfu(o.w);
        ((ushort4*)(outb + base))[lane] = ob;
    }
}

extern "C" void kernel_launch(void* const* d_in, const int* in_sizes, int n_in,
                              void* d_out, int out_size, void* d_ws, size_t ws_size,
                              hipStream_t stream) {
    const float* x   = (const float*)d_in[0];
    const float* wq  = (const float*)d_in[1];  const float* bq  = (const float*)d_in[2];
    const float* wk  = (const float*)d_in[3];  const float* bk  = (const float*)d_in[4];
    const float* wv  = (const float*)d_in[5];  const float* bv  = (const float*)d_in[6];
    const float* wo  = (const float*)d_in[7];  const float* wob = (const float*)d_in[8];
    const float* w1  = (const float*)d_in[9];  const float* b1  = (const float*)d_in[10];
    const float* w2  = (const float*)d_in[11]; const float* b2  = (const float*)d_in[12];
    const float* g1  = (const float*)d_in[13]; const float* bl1 = (const float*)d_in[14];
    const float* g2  = (const float*)d_in[15]; const float* bl2 = (const float*)d_in[16];

    char* ws = (char*)d_ws;
    unsigned short* xb    = (unsigned short*)(ws + B_XB);
    unsigned short* qb    = (unsigned short*)(ws + B_QB);
    unsigned short* kbuf  = (unsigned short*)(ws + B_KB);
    char*           vt    = (char*)(ws + B_VT);
    unsigned short* ctxb  = (unsigned short*)(ws + B_CTX);
    unsigned short* o1b   = (unsigned short*)(ws + B_O1B);
    float*          o1f   = (float*)(ws + B_O1F);
    unsigned short* mid   = (unsigned short*)(ws + B_MID);
    float*          c1    = (float*)(ws + B_MID);    // partials, dead before mid written
    float*          c2    = (float*)(ws + B_C2);     // partials, alias xb/qb/kb/vt (dead)
    unsigned short* wqkvT = (unsigned short*)(ws + B_WQKVT);
    unsigned short* woT   = (unsigned short*)(ws + B_WOT);
    unsigned short* w1T   = (unsigned short*)(ws + B_W1T);
    unsigned short* w2T   = (unsigned short*)(ws + B_W2T);
    float* bqkv = (float*)(ws + B_BQKV);
    float* hqb  = (float*)(ws + B_HQ);
    float* hkb  = (float*)(ws + B_HK);
    float* out  = (float*)d_out;

    k_packall<<<dim3(2819), dim3(256), 0, stream>>>(wq, wk, wv, wo, w1, w2, bq, bk, bv, x,
                                                    wqkvT, woT, w1T, w2T, bqkv, xb);
    k_qkv<<<dim3(64, 6), dim3(256), 0, stream>>>(xb, wqkvT, bqkv, qb, kbuf, vt);
    k_h2<<<dim3(256), dim3(256), 0, stream>>>(qb, kbuf, hqb, hkb);
    k_attn<<<dim3(1024), dim3(512), 0, stream>>>(qb, kbuf, vt, hqb, hkb, ctxb);
    k_gemm<256, 2, 256, 0, 1, 0><<<dim3(64, 2, 2), dim3(256), 0, stream>>>(ctxb, woT, wob, c1, nullptr);
    k_lnsum<1><<<dim3(2048), dim3(256), 0, stream>>>(c1, c1 + 2097152, x, g1, bl1, o1f, o1b);
    k_gemm<256, 4, 1024, 1, 0, 1><<<dim3(64, 8, 1), dim3(256), 0, stream>>>(o1b, w1T, b1, nullptr, mid);
    k_gemm<1024, 8, 256, 0, 1, 0><<<dim3(64, 2, 2), dim3(256), 0, stream>>>(mid, w2T, b2, c2, nullptr);
    k_lnsum<0><<<dim3(2048), dim3(256), 0, stream>>>(c2, c2 + 2097152, o1f, g2, bl2, out, nullptr);
}